// Round 11
// baseline (734.008 us; speedup 1.0000x reference)
//
#include <hip/hip_runtime.h>

typedef unsigned short u16;
typedef unsigned int   u32;

typedef __bf16 bf16_t;
typedef bf16_t bf16x8 __attribute__((ext_vector_type(8)));
typedef float  f32x4  __attribute__((ext_vector_type(4)));
typedef float  f32x16 __attribute__((ext_vector_type(16)));
typedef u16    u16x8  __attribute__((ext_vector_type(8)));
typedef u32    u32x4  __attribute__((ext_vector_type(4)));

__device__ __forceinline__ float bf2f(u16 u) { return __uint_as_float(((u32)u) << 16); }
__device__ __forceinline__ u16 f2bf(float f) {
  u32 u = __float_as_uint(f);
  u32 r = u + 0x7fffu + ((u >> 16) & 1u);
  return (u16)(r >> 16);
}
__device__ __forceinline__ float fast_exp2(float x) { return __builtin_amdgcn_exp2f(x); }

__device__ __forceinline__ void gload_lds16(const u16* g, u16* l) {
  __builtin_amdgcn_global_load_lds(
      (const __attribute__((address_space(1))) void*)g,
      (__attribute__((address_space(3))) void*)l,
      16, 0, 0);
}

#define SBAR0() __builtin_amdgcn_sched_barrier(0)
#define HWBAR() __builtin_amdgcn_s_barrier()

// ---------------- merged cast f32 -> bf16 into concat layouts (1 launch) ----------------
__global__ void k_cast_all(const float* __restrict__ x,  const float* __restrict__ wq,
                           const float* __restrict__ bq, const float* __restrict__ aq,
                           const float* __restrict__ wo, const float* __restrict__ bo,
                           const float* __restrict__ ao,
                           u16* __restrict__ xw, u16* __restrict__ wwq, u16* __restrict__ aqkvb,
                           u16* __restrict__ wwo, u16* __restrict__ aob) {
  const int total = 5177344;
  int i = blockIdx.x * blockDim.x + threadIdx.x;
  const int stride = gridDim.x * blockDim.x;
  for (; i < total; i += stride) {
    const float* src; u16* dst; int r, c8, L, off, sL;
    if (i < 1572864)      { int loc = i;           r = loc / 384; c8 = loc - r * 384; src = x;  dst = xw;    L = 3328; off = 0;    sL = 3072; }
    else if (i < 3538944) { int loc = i - 1572864; r = loc / 384; c8 = loc - r * 384; src = wq; dst = wwq;   L = 3328; off = 0;    sL = 3072; }
    else if (i < 3702784) { int loc = i - 3538944; r = loc >> 5;  c8 = loc & 31;      src = bq; dst = wwq;   L = 3328; off = 3072; sL = 256;  }
    else if (i < 3801088) { int loc = i - 3702784; r = loc / 384; c8 = loc - r * 384; src = aq; dst = aqkvb; L = 3072; off = 0;    sL = 3072; }
    else if (i < 4980736) { int loc = i - 3801088; r = loc / 384; c8 = loc - r * 384; src = wo; dst = wwo;   L = 3328; off = 0;    sL = 3072; }
    else if (i < 5079040) { int loc = i - 4980736; r = loc >> 5;  c8 = loc & 31;      src = bo; dst = wwo;   L = 3328; off = 3072; sL = 256;  }
    else                  { int loc = i - 5079040; r = loc / 384; c8 = loc - r * 384; src = ao; dst = aob;   L = 3072; off = 0;    sL = 3072; }
    const f32x4* p = (const f32x4*)(src + (size_t)r * sL + c8 * 8);
    f32x4 a = p[0], b2 = p[1];
    u16x8 o;
    o[0] = f2bf(a[0]);  o[1] = f2bf(a[1]);  o[2] = f2bf(a[2]);  o[3] = f2bf(a[3]);
    o[4] = f2bf(b2[0]); o[5] = f2bf(b2[1]); o[6] = f2bf(b2[2]); o[7] = f2bf(b2[3]);
    *(u16x8*)(dst + (size_t)r * L + off + c8 * 8) = o;
  }
}

// ---------------- reduce 4 f32 slabs + scale + strided cast to bf16 ----------------
__global__ void k_red4_cast(const float* __restrict__ t4, u16* __restrict__ out,
                            int C8, int L, int off, float scale, size_t plane) {
  const int r  = blockIdx.y;
  const int c8 = blockIdx.x * 64 + threadIdx.x;
  if (c8 >= C8) return;
  size_t base = (size_t)r * (C8 * 8) + c8 * 8;
  float s[8];
#pragma unroll
  for (int j = 0; j < 8; ++j) s[j] = 0.f;
#pragma unroll
  for (int p = 0; p < 4; ++p) {
    const f32x4* q = (const f32x4*)(t4 + p * plane + base);
    f32x4 a = q[0], b = q[1];
    s[0] += a[0]; s[1] += a[1]; s[2] += a[2]; s[3] += a[3];
    s[4] += b[0]; s[5] += b[1]; s[6] += b[2]; s[7] += b[3];
  }
  u16x8 o;
#pragma unroll
  for (int j = 0; j < 8; ++j) o[j] = f2bf(s[j] * scale);
  *(u16x8*)(out + (size_t)r * L + off + c8 * 8) = o;
}

// ---------------- small GEMM (64x64 tile), split-K slabs ----------------
__global__ __launch_bounds__(256) void k_gemm_bt_sk(
    const u16* __restrict__ A, const u16* __restrict__ B, float* __restrict__ C,
    int M, int N, int lda, int ldb, int kc) {
  __shared__ u16 As[64][64 + 8];
  __shared__ u16 Bs[64][64 + 8];
  const int tid   = threadIdx.x;
  const int lane  = tid & 63;
  const int w     = tid >> 6;
  const int wm    = (w >> 1) * 32;
  const int wn    = (w & 1) * 32;
  const int row16 = lane & 15;
  const int quad  = lane >> 4;
  const int m0 = blockIdx.y * 64;
  const int n0 = blockIdx.x * 64;
  const int ldr = tid >> 2;
  const int ldc = (tid & 3) * 16;
  const int z   = blockIdx.z;
  float* Cz = C + (size_t)z * M * N;
  const int kbeg = z * kc, kend = kbeg + kc;

  f32x4 acc[2][2] = {};

  for (int k0 = kbeg; k0 < kend; k0 += 64) {
    const u16* ga = A + (size_t)(m0 + ldr) * lda + (k0 + ldc);
    const u16* gb = B + (size_t)(n0 + ldr) * ldb + (k0 + ldc);
    u16x8 a0 = *(const u16x8*)ga;
    u16x8 a1 = *(const u16x8*)(ga + 8);
    u16x8 b0 = *(const u16x8*)gb;
    u16x8 b1 = *(const u16x8*)(gb + 8);
    __syncthreads();
    *(u16x8*)&As[ldr][ldc]     = a0;
    *(u16x8*)&As[ldr][ldc + 8] = a1;
    *(u16x8*)&Bs[ldr][ldc]     = b0;
    *(u16x8*)&Bs[ldr][ldc + 8] = b1;
    __syncthreads();
#pragma unroll
    for (int kk = 0; kk < 64; kk += 32) {
      bf16x8 af0 = *(const bf16x8*)&As[wm + row16][kk + quad * 8];
      bf16x8 af1 = *(const bf16x8*)&As[wm + 16 + row16][kk + quad * 8];
      bf16x8 bg0 = *(const bf16x8*)&Bs[wn + row16][kk + quad * 8];
      bf16x8 bg1 = *(const bf16x8*)&Bs[wn + 16 + row16][kk + quad * 8];
      acc[0][0] = __builtin_amdgcn_mfma_f32_16x16x32_bf16(af0, bg0, acc[0][0], 0, 0, 0);
      acc[0][1] = __builtin_amdgcn_mfma_f32_16x16x32_bf16(af0, bg1, acc[0][1], 0, 0, 0);
      acc[1][0] = __builtin_amdgcn_mfma_f32_16x16x32_bf16(af1, bg0, acc[1][0], 0, 0, 0);
      acc[1][1] = __builtin_amdgcn_mfma_f32_16x16x32_bf16(af1, bg1, acc[1][1], 0, 0, 0);
    }
  }
#pragma unroll
  for (int tm = 0; tm < 2; ++tm)
#pragma unroll
    for (int tn = 0; tn < 2; ++tn) {
      int gm = m0 + wm + tm * 16 + quad * 4;
      int gn = n0 + wn + tn * 16 + row16;
#pragma unroll
      for (int r = 0; r < 4; ++r)
        Cz[(size_t)(gm + r) * N + gn] = acc[tm][tn][r];
    }
}

// ================= 256x256 8-phase GEMM core, deep pipeline (R11) =================
// S = row stride of A/B (u16); K-extent via nt (A/B may be pre-offset in k).
// Deep schedule: tile k+2's B halves staged at q2 of tile k (B regions of buf k&1 are
// fully read by end of q1), A halves at q3 (A read ends q2). Boundary vmcnt(8): exactly
// tile k+2's 8 loads outstanding; tile k+1's loads (issued during tile k-1) landed.
__device__ __forceinline__ void stage_half(
    int H, int nt4,
    const u16* __restrict__ A, const u16* __restrict__ B, int S,
    int m0, int n0, u16* AsB, u16* BsB,
    int w, int rowin, int colsw) {
  if (H >= nt4) return;
  const int t = H >> 2, slot = H & 3;
  const int half = slot & 1;
  const u16* G = (slot < 2) ? A : B;
  const int r0 = (slot < 2) ? m0 : n0;
  u16* lds = ((slot < 2) ? AsB : BsB) + (t & 1) * 16384 + half * 8192;
  const int k0 = t * 64;
#pragma unroll
  for (int i = 0; i < 2; ++i) {
    const int chunk = w * 2 + i;
    const int row = half * 128 + chunk * 8 + rowin;
    gload_lds16(G + (size_t)(r0 + row) * S + k0 + colsw, lds + chunk * 512);
  }
}

__device__ __forceinline__ bf16x8 frag_ld(const u16* base, int row, int c16) {
  return *(const bf16x8*)(base + row * 64 + ((c16 ^ (row & 7)) << 3));
}

template <int RB>
__device__ __forceinline__ void gemm256_group(
    int k, int nt,
    const u16* __restrict__ A, const u16* __restrict__ B, int S,
    int m0, int n0, u16* AsB, u16* BsB,
    int wr, int wc, int row16, int quad, int w, int rowin, int colsw,
    f32x4 (&acc)[8][4]) {
  const u16* Ab = AsB + RB * 16384;
  const u16* Bb = BsB + RB * 16384;
  const int nt4 = nt * 4;
  bf16x8 a0[4][2], a1[4][2], b0[2][2], b1[2][2];

  // ---- q0: read A(mh0) + B(np0); MFMA (mh0,np0). No staging. ----
#pragma unroll
  for (int mf = 0; mf < 4; ++mf)
#pragma unroll
    for (int kk = 0; kk < 2; ++kk)
      a0[mf][kk] = frag_ld(Ab, wr * 128 + mf * 16 + row16, kk * 4 + quad);
#pragma unroll
  for (int nf = 0; nf < 2; ++nf)
#pragma unroll
    for (int kk = 0; kk < 2; ++kk)
      b0[nf][kk] = frag_ld(Bb, wc * 64 + nf * 16 + row16, kk * 4 + quad);
  SBAR0(); HWBAR(); SBAR0();
  __builtin_amdgcn_s_setprio(1);
#pragma unroll
  for (int mf = 0; mf < 4; ++mf)
#pragma unroll
    for (int nf = 0; nf < 2; ++nf)
#pragma unroll
      for (int kk = 0; kk < 2; ++kk)
        acc[mf][nf] = __builtin_amdgcn_mfma_f32_16x16x32_bf16(a0[mf][kk], b0[nf][kk], acc[mf][nf], 0, 0, 0);
  __builtin_amdgcn_s_setprio(0);
  SBAR0(); HWBAR(); SBAR0();

  // ---- q1: read B(np1); MFMA (mh0,np1). No staging. (All B reads done after q1.) ----
#pragma unroll
  for (int nf = 0; nf < 2; ++nf)
#pragma unroll
    for (int kk = 0; kk < 2; ++kk)
      b1[nf][kk] = frag_ld(Bb, wc * 64 + 32 + nf * 16 + row16, kk * 4 + quad);
  SBAR0(); HWBAR(); SBAR0();
  __builtin_amdgcn_s_setprio(1);
#pragma unroll
  for (int mf = 0; mf < 4; ++mf)
#pragma unroll
    for (int nf = 0; nf < 2; ++nf)
#pragma unroll
      for (int kk = 0; kk < 2; ++kk)
        acc[mf][2 + nf] = __builtin_amdgcn_mfma_f32_16x16x32_bf16(a0[mf][kk], b1[nf][kk], acc[mf][2 + nf], 0, 0, 0);
  __builtin_amdgcn_s_setprio(0);
  SBAR0(); HWBAR(); SBAR0();

  // ---- q2: read A(mh1); stage B halves of tile k+2 (B regions free); MFMA (mh1,np0) ----
#pragma unroll
  for (int mf = 0; mf < 4; ++mf)
#pragma unroll
    for (int kk = 0; kk < 2; ++kk)
      a1[mf][kk] = frag_ld(Ab, wr * 128 + 64 + mf * 16 + row16, kk * 4 + quad);
  stage_half(4 * k + 10, nt4, A, B, S, m0, n0, AsB, BsB, w, rowin, colsw);  // Bh0(k+2)
  stage_half(4 * k + 11, nt4, A, B, S, m0, n0, AsB, BsB, w, rowin, colsw);  // Bh1(k+2)
  SBAR0(); HWBAR(); SBAR0();
  __builtin_amdgcn_s_setprio(1);
#pragma unroll
  for (int mf = 0; mf < 4; ++mf)
#pragma unroll
    for (int nf = 0; nf < 2; ++nf)
#pragma unroll
      for (int kk = 0; kk < 2; ++kk)
        acc[4 + mf][nf] = __builtin_amdgcn_mfma_f32_16x16x32_bf16(a1[mf][kk], b0[nf][kk], acc[4 + mf][nf], 0, 0, 0);
  __builtin_amdgcn_s_setprio(0);
  SBAR0(); HWBAR(); SBAR0();

  // ---- q3: stage A halves of tile k+2 (A regions free after q2 barrier); boundary; MFMA ----
  stage_half(4 * k + 8, nt4, A, B, S, m0, n0, AsB, BsB, w, rowin, colsw);   // Ah0(k+2)
  stage_half(4 * k + 9, nt4, A, B, S, m0, n0, AsB, BsB, w, rowin, colsw);   // Ah1(k+2)
  SBAR0();
  if (k < nt - 2) { asm volatile("s_waitcnt vmcnt(8)" ::: "memory"); }
  else            { asm volatile("s_waitcnt vmcnt(0)" ::: "memory"); }
  HWBAR(); SBAR0();
  __builtin_amdgcn_s_setprio(1);
#pragma unroll
  for (int mf = 0; mf < 4; ++mf)
#pragma unroll
    for (int nf = 0; nf < 2; ++nf)
#pragma unroll
      for (int kk = 0; kk < 2; ++kk)
        acc[4 + mf][2 + nf] = __builtin_amdgcn_mfma_f32_16x16x32_bf16(a1[mf][kk], b1[nf][kk], acc[4 + mf][2 + nf], 0, 0, 0);
  __builtin_amdgcn_s_setprio(0);
  SBAR0(); HWBAR(); SBAR0();
}

// Full 256x256xK run. BF16OUT=1: store bf16 partials (split-K slab); else f32 stores.
template <int BF16OUT>
__device__ __forceinline__ void gemm256_run(
    const u16* __restrict__ A, const u16* __restrict__ B, int S, int nt,
    int m0, int n0, void* __restrict__ Cp, int ldc, int cn0,
    u16* As, u16* Bs) {
  const int tid   = threadIdx.x;
  const int lane  = tid & 63;
  const int w     = tid >> 6;
  const int wr    = w >> 2;
  const int wc    = w & 3;
  const int row16 = lane & 15;
  const int quad  = lane >> 4;
  const int rowin = lane >> 3;
  const int colsw = ((lane & 7) ^ (lane >> 3)) << 3;

  f32x4 acc[8][4] = {};

  // prologue: stage tiles 0 and 1 completely (16 loads); wait tile 0 (8 younger allowed)
#pragma unroll
  for (int H = 0; H < 8; ++H)
    stage_half(H, nt * 4, A, B, S, m0, n0, As, Bs, w, rowin, colsw);
  asm volatile("s_waitcnt vmcnt(8)" ::: "memory");
  HWBAR(); SBAR0();

  int k = 0;
  for (; k + 1 < nt; k += 2) {
    gemm256_group<0>(k,     nt, A, B, S, m0, n0, As, Bs, wr, wc, row16, quad, w, rowin, colsw, acc);
    gemm256_group<1>(k + 1, nt, A, B, S, m0, n0, As, Bs, wr, wc, row16, quad, w, rowin, colsw, acc);
  }
  if (k < nt)
    gemm256_group<0>(k, nt, A, B, S, m0, n0, As, Bs, wr, wc, row16, quad, w, rowin, colsw, acc);

#pragma unroll
  for (int mi = 0; mi < 8; ++mi) {
    const int gm = m0 + wr * 128 + mi * 16 + quad * 4;
#pragma unroll
    for (int nj = 0; nj < 4; ++nj) {
      const int gn = cn0 + wc * 64 + nj * 16 + row16;
#pragma unroll
      for (int r = 0; r < 4; ++r) {
        if (BF16OUT) ((u16*)Cp)[(size_t)(gm + r) * ldc + gn] = f2bf(acc[mi][nj][r]);
        else         ((float*)Cp)[(size_t)(gm + r) * ldc + gn] = acc[mi][nj][r];
      }
    }
  }
}

// generic wrapper (Wo GEMM): C(MxN) = A @ B^T, K = stride = extent
__global__ __launch_bounds__(512, 2) void k_gemm256(
    const u16* __restrict__ A, const u16* __restrict__ B, float* __restrict__ C,
    int M, int N, int K) {
  __shared__ u16 As[2 * 16384];
  __shared__ u16 Bs[2 * 16384];
  const int nwg = (int)gridDim.x;
  const int bid = (int)blockIdx.x;
  const int xcd = bid & 7, rest = bid >> 3;
  const int qq = nwg >> 3, rr = nwg & 7;
  const int wg = (xcd < rr ? xcd * (qq + 1) : rr * (qq + 1) + (xcd - rr) * qq) + rest;
  const int nbx = N >> 8;
  const int m0 = (wg / nbx) << 8;
  const int n0 = (wg % nbx) << 8;
  gemm256_run<0>(A, B, K, K >> 6, m0, n0, C, N, n0, As, Bs);
}

// qkv round 1: 256 blocks, one full-K q|k tile each -> Cqk[4096][4096] f32
__global__ __launch_bounds__(512, 2) void k_gemm256_qkv(
    const u16* __restrict__ A, const u16* __restrict__ B, float* __restrict__ Cqk) {
  __shared__ u16 As[2 * 16384];
  __shared__ u16 Bs[2 * 16384];
  const int bid = (int)blockIdx.x;
  const int xcd = bid & 7, rest = bid >> 3;
  const int wg = xcd * 32 + rest;          // nwg=256 -> qq=32, rr=0
  const int m0 = (wg >> 4) << 8;
  const int n0 = (wg & 15) << 8;
  gemm256_run<0>(A, B, 3328, 52, m0, n0, Cqk, 4096, n0, As, Bs);
}

// qkv round 2 FUSED with rope-qk (R11): 256 blocks.
// blocks 0..127 : one K-half (1664, 26 Kt) of a V-column tile -> bf16 slab Cvp[kc]
// blocks 128..255: rope on q|k reading Cqk -> qb, kb (which live in d_out scratch)
__global__ __launch_bounds__(512, 2) void k_qkv2(
    const u16* __restrict__ A, const u16* __restrict__ B,
    const float* __restrict__ qkf, u16* __restrict__ Cvp,
    const float* __restrict__ tab, u16* __restrict__ qb, u16* __restrict__ kb) {
  __shared__ u16 As[2 * 16384];
  __shared__ u16 Bs[2 * 16384];
  const int bid = (int)blockIdx.x;
  if (bid < 128) {
    const int m  = bid & 15;
    const int nv = (bid >> 4) & 3;
    const int kc = bid >> 6;                                  // 0 or 1
    const u16* At = A + kc * 1664;
    const u16* Bt = B + (size_t)4096 * 3328 + kc * 1664;      // V rows of wwq
    gemm256_run<1>(At, Bt, 3328, 26, m * 256, nv * 256,
                   Cvp + (size_t)kc * 4096 * 1024, 1024, nv * 256, As, Bs);
  } else {
    const int rb = bid - 128;            // 0..127
    const int g  = threadIdx.x >> 7;     // 0..3 (four 128-thread groups)
    const int d  = threadIdx.x & 127;
    for (int u = rb * 4 + g; u < 131072; u += 512) {
      const int r  = u >> 5;             // 0..4095
      const int hh = u & 31;             // 0..31: 0-23 q, 24-31 k
      const float* src;
      if (hh < 24) src = qkf + (size_t)r * 4096 + hh * 128;
      else         src = qkf + (size_t)r * 4096 + 3072 + (hh - 24) * 128;
      float x = src[d];
      float outv;
      if (d >= 96) {
        outv = x;
      } else {
        int j = (d < 48) ? d : d - 48;
        float c  = tab[(size_t)r * 96 + j];
        float sn = tab[(size_t)r * 96 + 48 + j];
        if (d < 48) outv = x * c - src[d + 48] * sn;
        else        outv = x * c + src[d - 48] * sn;
      }
      u16 o = f2bf(outv);
      if (hh < 24) qb[((size_t)r * 24 + hh) * 128 + d] = o;
      else         kb[((size_t)r * 8 + (hh - 24)) * 128 + d] = o;
    }
  }
}

// ---------------- RoPE cos/sin table (+ attn work-queue counter reset) ----------------
__global__ void k_rope_tab(const int* __restrict__ pos_ids, float* __restrict__ tab,
                           int* __restrict__ ctr) {
  if (blockIdx.x == 0 && threadIdx.x == 0) *ctr = 0;
  const int t = threadIdx.x;
  const int r = blockIdx.x * 4 + t / 48;
  const int j = t % 48;
  const float pos = (float)pos_ids[r];
  float invf = powf(10000.0f, -(float)j * (1.0f / 48.0f));
  float e = pos * invf;
  tab[(size_t)r * 96 + j]      = cosf(e);
  tab[(size_t)r * 96 + 48 + j] = sinf(e);
}

// ---------------- V transpose: sum 2 bf16 partial slabs -> vtg [b][kvh][d][key] ----------------
__global__ void k_vtrans(const u16* __restrict__ vp, u16* __restrict__ vtg) {
  const int d  = threadIdx.x;
  const int kg = blockIdx.x;
  const int bk = blockIdx.y;
  const int b = bk >> 3, kvh = bk & 7;
  const u16* s0 = vp + (size_t)(b * 2048 + kg * 8) * 1024 + kvh * 128 + d;
  const u16* s1 = s0 + (size_t)4096 * 1024;
  u16x8 pack;
#pragma unroll
  for (int t = 0; t < 8; ++t)
    pack[t] = f2bf(bf2f(s0[(size_t)t * 1024]) + bf2f(s1[(size_t)t * 1024]));
  *(u16x8*)(vtg + ((size_t)bk * 128 + d) * 2048 + kg * 8) = pack;
}

// ---------------- MFMA flash attention, 32x32, persistent work-queue (R8, frozen) ----------------
#define NJOBS 768

__global__ __launch_bounds__(256) void k_attn_mfma(
    const u16* __restrict__ qb, const u16* __restrict__ kb, const u16* __restrict__ vtg,
    u16* __restrict__ attnw, int* __restrict__ ctr) {
  __shared__ u16 Ks0[8192], Ks1[8192];
  __shared__ u16 Vt0[8192], Vt1[8192];
  __shared__ int s_job;

  const int tid  = threadIdx.x;
  const int lane = tid & 63;
  const int w    = tid >> 6;
  const int l31  = lane & 31;
  const int hi   = lane >> 5;
  const int r7   = lane & 7;
  const float C1 = 0.08838834764831845f * 1.4426950408889634f;

  for (;;) {
    if (tid == 0) s_job = atomicAdd(ctr, 1);
    __syncthreads();
    const int j = s_job;
    if (j >= NJOBS) return;

    const int qt  = 15 - (j / 48);
    const int bh  = j % 48;
    const int b   = bh / 24;
    const int h   = bh % 24;
    const int kvh = h / 3;
    const int q0  = qt * 128;
    const int qrow = q0 + w * 32 + l31;

    const u16* qrb = qb + (((size_t)(b * 2048 + qrow)) * 24 + h) * 128;
    bf16x8 qf[8];
#pragma unroll
    for (int kk = 0; kk < 8; ++kk) qf[kk] = *(const bf16x8*)(qrb + kk * 16 + hi * 8);

    const u16* kbbase = kb + ((size_t)(b * 2048) * 8 + kvh) * 128;
    const u16* vtbase = vtg + (size_t)(b * 8 + kvh) * 128 * 2048;

    f32x16 o32[4] = {};
    float m_st = -INFINITY, l_st = 0.f;
    const int ntile = 2 * qt + 2;

#define STAGE_K(Kd, KB0)                                                        \
  { _Pragma("unroll") for (int i = 0; i < 4; ++i) {                             \
      const int c = w * 4 + i;                                                  \
      const int rowk = 4 * c + (lane >> 4);                                     \
      gload_lds16(kbbase + (size_t)((KB0) + rowk) * 1024 +                      \
                      (((lane & 15) ^ (rowk & 7)) << 3),                        \
                  (Kd) + c * 512); } }
#define STAGE_V(Vd, KB0)                                                        \
  { _Pragma("unroll") for (int i = 0; i < 4; ++i) {                             \
      const int c = w * 4 + i;                                                  \
      const int rowv = 8 * c + (lane >> 3);                                     \
      gload_lds16(vtbase + (size_t)rowv * 2048 + (KB0) +                        \
                      (((lane & 7) ^ (rowv & 7)) << 3),                         \
                  (Vd) + c * 512); } }

    STAGE_K(Ks0, 0);
    STAGE_V(Vt0, 0);

    for (int t = 0; t < ntile; ++t) {
      const int kb0 = t * 64;
      const u16* Kc = (t & 1) ? Ks1 : Ks0;
      const u16* Vc = (t & 1) ? Vt1 : Vt0;

      asm volatile("s_waitcnt vmcnt(0)" ::: "memory");
      SBAR0(); HWBAR(); SBAR0();
      if (t + 1 < ntile) {
        u16* Kn = (t & 1) ? Ks0 : Ks1;
        u16* Vn = (t & 1) ? Vt0 : Vt1;
        STAGE_K(Kn, kb0 + 64);
        STAGE_V(Vn, kb0 + 64);
      }
      SBAR0();

      f32x16 s0 = {}, s1 = {};
      __builtin_amdgcn_s_setprio(1);
#pragma unroll
      for (int kk = 0; kk < 8; ++kk) {
        bf16x8 kf0 = *(const bf16x8*)&Kc[l31 * 128 + (((2 * kk + hi) ^ r7) << 3)];
        s0 = __builtin_amdgcn_mfma_f32_32x32x16_bf16(kf0, qf[kk], s0, 0, 0, 0);
        bf16x8 kf1 = *(const bf16x8*)&Kc[(32 + l31) * 128 + (((2 * kk + hi) ^ ((32 + l31) & 7)) << 3)];
        s1 = __builtin_amdgcn_mfma_f32_32x32x16_bf16(kf1, qf[kk], s1, 0, 0, 0);
      }
      __builtin_amdgcn_s_setprio(0);

      if (kb0 >= q0) {
#pragma unroll
        for (int r = 0; r < 16; ++r) {
          const int crow = (r & 3) + 8 * (r >> 2) + 4 * hi;
          if (kb0 + crow > qrow)      s0[r] = -INFINITY;
          if (kb0 + 32 + crow > qrow) s1[r] = -INFINITY;
        }
      }

      float tm[8];
#pragma unroll
      for (int r = 0; r < 8; ++r)
        tm[r] = fmaxf(fmaxf(s0[r], s0[r + 8]), fmaxf(s1[r], s1[r + 8]));
#pragma unroll
      for (int st = 4; st >= 1; st >>= 1)
#pragma unroll
        for (int r = 0; r < 4; ++r)
          if (r < st) tm[r] = fmaxf(tm[r], tm[r + st]);
      float mx = fmaxf(tm[0], __shfl_xor(tm[0], 32));

      const bool skip = __all((mx - m_st) * C1 <= 8.0f);
      if (!skip) {
        const float mnew = fmaxf(m_st, mx);
        const float alpha = fast_exp2((m_st - mnew) * C1);
        l_st *= alpha;
#pragma unroll
        for (int dt = 0; dt < 4; ++dt)
#pragma unroll
          for (int r = 0; r < 16; ++r) o32[dt][r] *= alpha;
        m_st = mnew;
      }
      const float mc = m_st * C1;
      float ts[8];
#pragma unroll
      for (int r = 0; r < 16; ++r) {
        s0[r] = fast_exp2(__builtin_fmaf(s0[r], C1, -mc));
        s1[r] = fast_exp2(__builtin_fmaf(s1[r], C1, -mc));
      }
#pragma unroll
      for (int r = 0; r < 8; ++r) ts[r] = (s0[r] + s0[r + 8]) + (s1[r] + s1[r + 8]);
#pragma unroll
      for (int st = 4; st >= 1; st >>= 1)
#pragma unroll
        for (int r = 0; r < 4; ++r)
          if (r < st) ts[r] += ts[r + st];
      l_st += ts[0] + __shfl_xor(ts[0], 32);

#pragma unroll
      for (int kt = 0; kt < 2; ++kt) {
        const f32x16& sv = kt ? s1 : s0;
        u32 pk[8];
#pragma unroll
        for (int i = 0; i < 8; ++i)
          asm("v_cvt_pk_bf16_f32 %0, %1, %2"
              : "=v"(pk[i]) : "v"(sv[2 * i]), "v"(sv[2 * i + 1]));
        u32 e0 = __shfl_xor(hi ? pk[0] : pk[2], 32);
        u32 e1 = __shfl_xor(hi ? pk[1] : pk[3], 32);
        u32 e2 = __shfl_xor(hi ? pk[4] : pk[6], 32);
        u32 e3 = __shfl_xor(hi ? pk[5] : pk[7], 32);
        u32x4 w0, w1;
        w0[0] = hi ? e0 : pk[0]; w0[1] = hi ? e1 : pk[1];
        w0[2] = hi ? pk[2] : e0; w0[3] = hi ? pk[3] : e1;
        w1[0] = hi ? e2 : pk[4]; w1[1] = hi ? e3 : pk[5];
        w1[2] = hi ? pk[6] : e2; w1[3] = hi ? pk[7] : e3;
        bf16x8 pb0 = __builtin_bit_cast(bf16x8, w0);
        bf16x8 pb1 = __builtin_bit_cast(bf16x8, w1);
        __builtin_amdgcn_s_setprio(1);
#pragma unroll
        for (int dt = 0; dt < 4; ++dt) {
          const int vrow = dt * 32 + l31;
          bf16x8 vf0 = *(const bf16x8*)&Vc[vrow * 64 + (((2 * (2 * kt) + hi) ^ (vrow & 7)) << 3)];
          o32[dt] = __builtin_amdgcn_mfma_f32_32x32x16_bf16(vf0, pb0, o32[dt], 0, 0, 0);
          bf16x8 vf1 = *(const bf16x8*)&Vc[vrow * 64 + (((2 * (2 * kt + 1) + hi) ^ (vrow & 7)) << 3)];
          o32[dt] = __builtin_amdgcn_mfma_f32_32x32x16_bf16(vf1, pb1, o32[dt], 0, 0, 0);
        }
        __builtin_amdgcn_s_setprio(0);
      }
    }

    __syncthreads();
    const float inv = 1.0f / l_st;
    u16* scr = ((w < 2) ? Ks0 : Ks1) + (w & 1) * 4096;
#pragma unroll
    for (int dt = 0; dt < 4; ++dt)
#pragma unroll
      for (int r = 0; r < 16; ++r) {
        const int d = 32 * dt + (r & 3) + 8 * (r >> 2) + 4 * hi;
        const int slot = (d >> 3) ^ (l31 & 7);
        scr[l31 * 128 + slot * 8 + (d & 7)] = f2bf(o32[dt][r] * inv);
      }
    const int q32r = lane >> 1, part = lane & 1;
    const size_t grow = ((size_t)(b * 2048 + q0 + w * 32 + q32r)) * 3328 + (size_t)h * 128;
#pragma unroll
    for (int c = 0; c < 8; ++c) {
      const int d0 = part * 64 + c * 8;
      const int s2 = (d0 >> 3) ^ (q32r & 7);
      *(u16x8*)(attnw + grow + d0) = *(const u16x8*)&scr[q32r * 128 + s2 * 8];
    }
  }
}

// ---------------- workspace layout (bytes), total 173,015,040 ----------------
#define OFF_XW    ((size_t)0)
#define OFF_WWQ   ((size_t)27262976)
#define OFF_AQKVB ((size_t)61341696)
#define OFF_WWO   ((size_t)62914560)
#define OFF_AOB   ((size_t)83361792)
#define OFF_QKV   ((size_t)84934656)               // Cqk [4096][4096] f32 = 67108864
#define OFF_CVP   (OFF_QKV + (size_t)67108864)     // Cvp [2][4096][1024] bf16 = 16777216
#define OFF_RTAB  (OFF_CVP + (size_t)16777216)     // 1572864 (true tail; never overlaps live data)
#define OFF_CTR   (OFF_RTAB + (size_t)1572864)     // 4 B
#define OFF_TA4   OFF_QKV
#define OFF_VTG   (OFF_WWQ + (size_t)8388608)      // wwq dead after k_qkv2
#define OFF_ATTNW OFF_QKV                          // Cqk dead after k_qkv2
#define OFF_TO4   (OFF_QKV + (size_t)27262976)
// qb (24 MB) and kb (8 MB) live in d_out scratch (50 MB, fully overwritten by Wo GEMM)

extern "C" void kernel_launch(void* const* d_in, const int* in_sizes, int n_in,
                              void* d_out, int out_size, void* d_ws, size_t ws_size,
                              hipStream_t stream) {
  const float* x    = (const float*)d_in[0];
  const float* Wqkv = (const float*)d_in[1];
  const float* Aqkv = (const float*)d_in[2];
  const float* Bqkv = (const float*)d_in[3];
  const float* Wo   = (const float*)d_in[4];
  const float* Ao   = (const float*)d_in[5];
  const float* Bo   = (const float*)d_in[6];
  const int*   pos  = (const int*)d_in[7];
  float* out = (float*)d_out;
  char* ws = (char*)d_ws;

  u16* xw    = (u16*)(ws + OFF_XW);
  u16* wwq   = (u16*)(ws + OFF_WWQ);
  u16* aqkvb = (u16*)(ws + OFF_AQKVB);
  u16* wwo   = (u16*)(ws + OFF_WWO);
  u16* aob   = (u16*)(ws + OFF_AOB);
  float* qk  = (float*)(ws + OFF_QKV);
  u16* cvp   = (u16*)(ws + OFF_CVP);
  float* rtab = (float*)(ws + OFF_RTAB);
  int* ctr   = (int*)(ws + OFF_CTR);
  float* tA4 = (float*)(ws + OFF_TA4);
  u16* vtg   = (u16*)(ws + OFF_VTG);
  u16* attnw = (u16*)(ws + OFF_ATTNW);
  float* tO4 = (float*)(ws + OFF_TO4);
  u16* qb    = (u16*)d_out;                         // 24 MB scratch in d_out
  u16* kb    = (u16*)((char*)d_out + 25165824);     // 8 MB scratch in d_out

  // 1) all casts in one launch
  k_cast_all<<<2048, 256, 0, stream>>>(x, Wqkv, Bqkv, Aqkv, Wo, Bo, Ao,
                                       xw, wwq, aqkvb, wwo, aob);

  // 2) LoRA-A: tA = x @ Aqkv^T (split-K x4) -> xw tail (scaled by 2)
  k_gemm_bt_sk<<<dim3(4, 64, 4), 256, 0, stream>>>(xw, aqkvb, tA4, 4096, 256, 3328, 3072, 768);
  k_red4_cast<<<dim3(1, 4096), 64, 0, stream>>>(tA4, xw, 32, 3328, 3072, 2.f, (size_t)4096 * 256);

  // 3) rope table + ctr reset (rtab now in true workspace tail, safe before qkv)
  k_rope_tab<<<dim3(1024), 192, 0, stream>>>(pos, rtab, ctr);

  // 4) qkv round 1: q|k tiles full-K -> Cqk
  k_gemm256_qkv<<<dim3(256), 512, 0, stream>>>(xw, wwq, qk);

  // 5) FUSED: V-tile split-K GEMM (128 blocks) || rope-qk (128 blocks)
  k_qkv2<<<dim3(256), 512, 0, stream>>>(xw, wwq, qk, cvp, rtab, qb, kb);

  // 6) V transpose (sum slabs) -> vtg
  k_vtrans<<<dim3(256, 16), 128, 0, stream>>>(cvp, vtg);

  // 7) MFMA flash attention (persistent, work-queue) -> attnw (stride 3328)
  k_attn_mfma<<<dim3(512), 256, 0, stream>>>(qb, kb, vtg, attnw, ctr);

  // 8) LoRA-A out: tO = attn @ Ao^T (split-K x4) -> attnw tail (scaled by 2)
  k_gemm_bt_sk<<<dim3(4, 64, 4), 256, 0, stream>>>(attnw, aob, tO4, 4096, 256, 3328, 3072, 768);
  k_red4_cast<<<dim3(1, 4096), 64, 0, stream>>>(tO4, attnw, 32, 3328, 3072, 2.f, (size_t)4096 * 256);

  // 9) out = [attn | 2 tO] @ [Wo | Bo]^T  (K=3328)
  k_gemm256<<<dim3((3072 / 256) * (4096 / 256)), 512, 0, stream>>>(attnw, wwo, out, 4096, 3072, 3328);
}

// Round 12
// 650.848 us; speedup vs baseline: 1.1278x; 1.1278x over previous
//
#include <hip/hip_runtime.h>

typedef unsigned short u16;
typedef unsigned int   u32;

typedef __bf16 bf16_t;
typedef bf16_t bf16x8 __attribute__((ext_vector_type(8)));
typedef float  f32x4  __attribute__((ext_vector_type(4)));
typedef float  f32x16 __attribute__((ext_vector_type(16)));
typedef u16    u16x8  __attribute__((ext_vector_type(8)));
typedef u32    u32x4  __attribute__((ext_vector_type(4)));

__device__ __forceinline__ float bf2f(u16 u) { return __uint_as_float(((u32)u) << 16); }
__device__ __forceinline__ u16 f2bf(float f) {
  u32 u = __float_as_uint(f);
  u32 r = u + 0x7fffu + ((u >> 16) & 1u);
  return (u16)(r >> 16);
}
__device__ __forceinline__ float fast_exp2(float x) { return __builtin_amdgcn_exp2f(x); }

__device__ __forceinline__ void gload_lds16(const u16* g, u16* l) {
  __builtin_amdgcn_global_load_lds(
      (const __attribute__((address_space(1))) void*)g,
      (__attribute__((address_space(3))) void*)l,
      16, 0, 0);
}

#define SBAR0() __builtin_amdgcn_sched_barrier(0)
#define HWBAR() __builtin_amdgcn_s_barrier()

// ---------------- merged cast f32 -> bf16 into concat layouts (1 launch) ----------------
__global__ void k_cast_all(const float* __restrict__ x,  const float* __restrict__ wq,
                           const float* __restrict__ bq, const float* __restrict__ aq,
                           const float* __restrict__ wo, const float* __restrict__ bo,
                           const float* __restrict__ ao,
                           u16* __restrict__ xw, u16* __restrict__ wwq, u16* __restrict__ aqkvb,
                           u16* __restrict__ wwo, u16* __restrict__ aob) {
  const int total = 5177344;
  int i = blockIdx.x * blockDim.x + threadIdx.x;
  const int stride = gridDim.x * blockDim.x;
  for (; i < total; i += stride) {
    const float* src; u16* dst; int r, c8, L, off, sL;
    if (i < 1572864)      { int loc = i;           r = loc / 384; c8 = loc - r * 384; src = x;  dst = xw;    L = 3328; off = 0;    sL = 3072; }
    else if (i < 3538944) { int loc = i - 1572864; r = loc / 384; c8 = loc - r * 384; src = wq; dst = wwq;   L = 3328; off = 0;    sL = 3072; }
    else if (i < 3702784) { int loc = i - 3538944; r = loc >> 5;  c8 = loc & 31;      src = bq; dst = wwq;   L = 3328; off = 3072; sL = 256;  }
    else if (i < 3801088) { int loc = i - 3702784; r = loc / 384; c8 = loc - r * 384; src = aq; dst = aqkvb; L = 3072; off = 0;    sL = 3072; }
    else if (i < 4980736) { int loc = i - 3801088; r = loc / 384; c8 = loc - r * 384; src = wo; dst = wwo;   L = 3328; off = 0;    sL = 3072; }
    else if (i < 5079040) { int loc = i - 4980736; r = loc >> 5;  c8 = loc & 31;      src = bo; dst = wwo;   L = 3328; off = 3072; sL = 256;  }
    else                  { int loc = i - 5079040; r = loc / 384; c8 = loc - r * 384; src = ao; dst = aob;   L = 3072; off = 0;    sL = 3072; }
    const f32x4* p = (const f32x4*)(src + (size_t)r * sL + c8 * 8);
    f32x4 a = p[0], b2 = p[1];
    u16x8 o;
    o[0] = f2bf(a[0]);  o[1] = f2bf(a[1]);  o[2] = f2bf(a[2]);  o[3] = f2bf(a[3]);
    o[4] = f2bf(b2[0]); o[5] = f2bf(b2[1]); o[6] = f2bf(b2[2]); o[7] = f2bf(b2[3]);
    *(u16x8*)(dst + (size_t)r * L + off + c8 * 8) = o;
  }
}

// ---------------- reduce 4 f32 slabs + scale + strided cast to bf16 ----------------
__global__ void k_red4_cast(const float* __restrict__ t4, u16* __restrict__ out,
                            int C8, int L, int off, float scale, size_t plane) {
  const int r  = blockIdx.y;
  const int c8 = blockIdx.x * 64 + threadIdx.x;
  if (c8 >= C8) return;
  size_t base = (size_t)r * (C8 * 8) + c8 * 8;
  float s[8];
#pragma unroll
  for (int j = 0; j < 8; ++j) s[j] = 0.f;
#pragma unroll
  for (int p = 0; p < 4; ++p) {
    const f32x4* q = (const f32x4*)(t4 + p * plane + base);
    f32x4 a = q[0], b = q[1];
    s[0] += a[0]; s[1] += a[1]; s[2] += a[2]; s[3] += a[3];
    s[4] += b[0]; s[5] += b[1]; s[6] += b[2]; s[7] += b[3];
  }
  u16x8 o;
#pragma unroll
  for (int j = 0; j < 8; ++j) o[j] = f2bf(s[j] * scale);
  *(u16x8*)(out + (size_t)r * L + off + c8 * 8) = o;
}

// ---------------- small GEMM (64x64 tile), split-K slabs ----------------
__global__ __launch_bounds__(256) void k_gemm_bt_sk(
    const u16* __restrict__ A, const u16* __restrict__ B, float* __restrict__ C,
    int M, int N, int lda, int ldb, int kc) {
  __shared__ u16 As[64][64 + 8];
  __shared__ u16 Bs[64][64 + 8];
  const int tid   = threadIdx.x;
  const int lane  = tid & 63;
  const int w     = tid >> 6;
  const int wm    = (w >> 1) * 32;
  const int wn    = (w & 1) * 32;
  const int row16 = lane & 15;
  const int quad  = lane >> 4;
  const int m0 = blockIdx.y * 64;
  const int n0 = blockIdx.x * 64;
  const int ldr = tid >> 2;
  const int ldc = (tid & 3) * 16;
  const int z   = blockIdx.z;
  float* Cz = C + (size_t)z * M * N;
  const int kbeg = z * kc, kend = kbeg + kc;

  f32x4 acc[2][2] = {};

  for (int k0 = kbeg; k0 < kend; k0 += 64) {
    const u16* ga = A + (size_t)(m0 + ldr) * lda + (k0 + ldc);
    const u16* gb = B + (size_t)(n0 + ldr) * ldb + (k0 + ldc);
    u16x8 a0 = *(const u16x8*)ga;
    u16x8 a1 = *(const u16x8*)(ga + 8);
    u16x8 b0 = *(const u16x8*)gb;
    u16x8 b1 = *(const u16x8*)(gb + 8);
    __syncthreads();
    *(u16x8*)&As[ldr][ldc]     = a0;
    *(u16x8*)&As[ldr][ldc + 8] = a1;
    *(u16x8*)&Bs[ldr][ldc]     = b0;
    *(u16x8*)&Bs[ldr][ldc + 8] = b1;
    __syncthreads();
#pragma unroll
    for (int kk = 0; kk < 64; kk += 32) {
      bf16x8 af0 = *(const bf16x8*)&As[wm + row16][kk + quad * 8];
      bf16x8 af1 = *(const bf16x8*)&As[wm + 16 + row16][kk + quad * 8];
      bf16x8 bg0 = *(const bf16x8*)&Bs[wn + row16][kk + quad * 8];
      bf16x8 bg1 = *(const bf16x8*)&Bs[wn + 16 + row16][kk + quad * 8];
      acc[0][0] = __builtin_amdgcn_mfma_f32_16x16x32_bf16(af0, bg0, acc[0][0], 0, 0, 0);
      acc[0][1] = __builtin_amdgcn_mfma_f32_16x16x32_bf16(af0, bg1, acc[0][1], 0, 0, 0);
      acc[1][0] = __builtin_amdgcn_mfma_f32_16x16x32_bf16(af1, bg0, acc[1][0], 0, 0, 0);
      acc[1][1] = __builtin_amdgcn_mfma_f32_16x16x32_bf16(af1, bg1, acc[1][1], 0, 0, 0);
    }
  }
#pragma unroll
  for (int tm = 0; tm < 2; ++tm)
#pragma unroll
    for (int tn = 0; tn < 2; ++tn) {
      int gm = m0 + wm + tm * 16 + quad * 4;
      int gn = n0 + wn + tn * 16 + row16;
#pragma unroll
      for (int r = 0; r < 4; ++r)
        Cz[(size_t)(gm + r) * N + gn] = acc[tm][tn][r];
    }
}

// ================= 256x256 8-phase GEMM core, deep pipeline (R11-verified) =================
// Tile k+2's B halves staged at q2 of tile k (B regions of buf k&1 fully read by end q1),
// A halves at q3 (A reads end q2). Boundary vmcnt(8): tile k+2's 8 loads outstanding,
// tile k+1's landed. Correctness verified in R11 (absmax unchanged on all GEMMs).
__device__ __forceinline__ void stage_half(
    int H, int nt4,
    const u16* __restrict__ A, const u16* __restrict__ B, int S,
    int m0, int n0, u16* AsB, u16* BsB,
    int w, int rowin, int colsw) {
  if (H >= nt4) return;
  const int t = H >> 2, slot = H & 3;
  const int half = slot & 1;
  const u16* G = (slot < 2) ? A : B;
  const int r0 = (slot < 2) ? m0 : n0;
  u16* lds = ((slot < 2) ? AsB : BsB) + (t & 1) * 16384 + half * 8192;
  const int k0 = t * 64;
#pragma unroll
  for (int i = 0; i < 2; ++i) {
    const int chunk = w * 2 + i;
    const int row = half * 128 + chunk * 8 + rowin;
    gload_lds16(G + (size_t)(r0 + row) * S + k0 + colsw, lds + chunk * 512);
  }
}

__device__ __forceinline__ bf16x8 frag_ld(const u16* base, int row, int c16) {
  return *(const bf16x8*)(base + row * 64 + ((c16 ^ (row & 7)) << 3));
}

template <int RB>
__device__ __forceinline__ void gemm256_group(
    int k, int nt,
    const u16* __restrict__ A, const u16* __restrict__ B, int S,
    int m0, int n0, u16* AsB, u16* BsB,
    int wr, int wc, int row16, int quad, int w, int rowin, int colsw,
    f32x4 (&acc)[8][4]) {
  const u16* Ab = AsB + RB * 16384;
  const u16* Bb = BsB + RB * 16384;
  const int nt4 = nt * 4;
  bf16x8 a0[4][2], a1[4][2], b0[2][2], b1[2][2];

  // q0: read A(mh0)+B(np0); MFMA (mh0,np0)
#pragma unroll
  for (int mf = 0; mf < 4; ++mf)
#pragma unroll
    for (int kk = 0; kk < 2; ++kk)
      a0[mf][kk] = frag_ld(Ab, wr * 128 + mf * 16 + row16, kk * 4 + quad);
#pragma unroll
  for (int nf = 0; nf < 2; ++nf)
#pragma unroll
    for (int kk = 0; kk < 2; ++kk)
      b0[nf][kk] = frag_ld(Bb, wc * 64 + nf * 16 + row16, kk * 4 + quad);
  SBAR0(); HWBAR(); SBAR0();
  __builtin_amdgcn_s_setprio(1);
#pragma unroll
  for (int mf = 0; mf < 4; ++mf)
#pragma unroll
    for (int nf = 0; nf < 2; ++nf)
#pragma unroll
      for (int kk = 0; kk < 2; ++kk)
        acc[mf][nf] = __builtin_amdgcn_mfma_f32_16x16x32_bf16(a0[mf][kk], b0[nf][kk], acc[mf][nf], 0, 0, 0);
  __builtin_amdgcn_s_setprio(0);
  SBAR0(); HWBAR(); SBAR0();

  // q1: read B(np1); MFMA (mh0,np1). All B reads of this buf done after q1.
#pragma unroll
  for (int nf = 0; nf < 2; ++nf)
#pragma unroll
    for (int kk = 0; kk < 2; ++kk)
      b1[nf][kk] = frag_ld(Bb, wc * 64 + 32 + nf * 16 + row16, kk * 4 + quad);
  SBAR0(); HWBAR(); SBAR0();
  __builtin_amdgcn_s_setprio(1);
#pragma unroll
  for (int mf = 0; mf < 4; ++mf)
#pragma unroll
    for (int nf = 0; nf < 2; ++nf)
#pragma unroll
      for (int kk = 0; kk < 2; ++kk)
        acc[mf][2 + nf] = __builtin_amdgcn_mfma_f32_16x16x32_bf16(a0[mf][kk], b1[nf][kk], acc[mf][2 + nf], 0, 0, 0);
  __builtin_amdgcn_s_setprio(0);
  SBAR0(); HWBAR(); SBAR0();

  // q2: read A(mh1); stage B halves of tile k+2; MFMA (mh1,np0)
#pragma unroll
  for (int mf = 0; mf < 4; ++mf)
#pragma unroll
    for (int kk = 0; kk < 2; ++kk)
      a1[mf][kk] = frag_ld(Ab, wr * 128 + 64 + mf * 16 + row16, kk * 4 + quad);
  stage_half(4 * k + 10, nt4, A, B, S, m0, n0, AsB, BsB, w, rowin, colsw);
  stage_half(4 * k + 11, nt4, A, B, S, m0, n0, AsB, BsB, w, rowin, colsw);
  SBAR0(); HWBAR(); SBAR0();
  __builtin_amdgcn_s_setprio(1);
#pragma unroll
  for (int mf = 0; mf < 4; ++mf)
#pragma unroll
    for (int nf = 0; nf < 2; ++nf)
#pragma unroll
      for (int kk = 0; kk < 2; ++kk)
        acc[4 + mf][nf] = __builtin_amdgcn_mfma_f32_16x16x32_bf16(a1[mf][kk], b0[nf][kk], acc[4 + mf][nf], 0, 0, 0);
  __builtin_amdgcn_s_setprio(0);
  SBAR0(); HWBAR(); SBAR0();

  // q3: stage A halves of tile k+2; boundary vmcnt; MFMA (mh1,np1)
  stage_half(4 * k + 8, nt4, A, B, S, m0, n0, AsB, BsB, w, rowin, colsw);
  stage_half(4 * k + 9, nt4, A, B, S, m0, n0, AsB, BsB, w, rowin, colsw);
  SBAR0();
  if (k < nt - 2) { asm volatile("s_waitcnt vmcnt(8)" ::: "memory"); }
  else            { asm volatile("s_waitcnt vmcnt(0)" ::: "memory"); }
  HWBAR(); SBAR0();
  __builtin_amdgcn_s_setprio(1);
#pragma unroll
  for (int mf = 0; mf < 4; ++mf)
#pragma unroll
    for (int nf = 0; nf < 2; ++nf)
#pragma unroll
      for (int kk = 0; kk < 2; ++kk)
        acc[4 + mf][2 + nf] = __builtin_amdgcn_mfma_f32_16x16x32_bf16(a1[mf][kk], b1[nf][kk], acc[4 + mf][2 + nf], 0, 0, 0);
  __builtin_amdgcn_s_setprio(0);
  SBAR0(); HWBAR(); SBAR0();
}

// Full 256x256xK run. BF16OUT=1: store bf16 partials (split-K slab); else f32 stores.
template <int BF16OUT>
__device__ __forceinline__ void gemm256_run(
    const u16* __restrict__ A, const u16* __restrict__ B, int S, int nt,
    int m0, int n0, void* __restrict__ Cp, int ldc, int cn0,
    u16* As, u16* Bs) {
  const int tid   = threadIdx.x;
  const int lane  = tid & 63;
  const int w     = tid >> 6;
  const int wr    = w >> 2;
  const int wc    = w & 3;
  const int row16 = lane & 15;
  const int quad  = lane >> 4;
  const int rowin = lane >> 3;
  const int colsw = ((lane & 7) ^ (lane >> 3)) << 3;

  f32x4 acc[8][4] = {};

  // prologue: stage tiles 0,1 completely (16 loads/wave); wait tile 0 (8 younger allowed)
#pragma unroll
  for (int H = 0; H < 8; ++H)
    stage_half(H, nt * 4, A, B, S, m0, n0, As, Bs, w, rowin, colsw);
  asm volatile("s_waitcnt vmcnt(8)" ::: "memory");
  HWBAR(); SBAR0();

  int k = 0;
  for (; k + 1 < nt; k += 2) {
    gemm256_group<0>(k,     nt, A, B, S, m0, n0, As, Bs, wr, wc, row16, quad, w, rowin, colsw, acc);
    gemm256_group<1>(k + 1, nt, A, B, S, m0, n0, As, Bs, wr, wc, row16, quad, w, rowin, colsw, acc);
  }
  if (k < nt)
    gemm256_group<0>(k, nt, A, B, S, m0, n0, As, Bs, wr, wc, row16, quad, w, rowin, colsw, acc);

#pragma unroll
  for (int mi = 0; mi < 8; ++mi) {
    const int gm = m0 + wr * 128 + mi * 16 + quad * 4;
#pragma unroll
    for (int nj = 0; nj < 4; ++nj) {
      const int gn = cn0 + wc * 64 + nj * 16 + row16;
#pragma unroll
      for (int r = 0; r < 4; ++r) {
        if (BF16OUT) ((u16*)Cp)[(size_t)(gm + r) * ldc + gn] = f2bf(acc[mi][nj][r]);
        else         ((float*)Cp)[(size_t)(gm + r) * ldc + gn] = acc[mi][nj][r];
      }
    }
  }
}

// generic wrapper (Wo GEMM): C(MxN) = A @ B^T, K = stride = extent
__global__ __launch_bounds__(512, 2) void k_gemm256(
    const u16* __restrict__ A, const u16* __restrict__ B, float* __restrict__ C,
    int M, int N, int K) {
  __shared__ u16 As[2 * 16384];
  __shared__ u16 Bs[2 * 16384];
  const int nwg = (int)gridDim.x;
  const int bid = (int)blockIdx.x;
  const int xcd = bid & 7, rest = bid >> 3;
  const int qq = nwg >> 3, rr = nwg & 7;
  const int wg = (xcd < rr ? xcd * (qq + 1) : rr * (qq + 1) + (xcd - rr) * qq) + rest;
  const int nbx = N >> 8;
  const int m0 = (wg / nbx) << 8;
  const int n0 = (wg % nbx) << 8;
  gemm256_run<0>(A, B, K, K >> 6, m0, n0, C, N, n0, As, Bs);
}

// qkv GEMM, grid-quantization-balanced, no atomics (R10 structure + deep pipeline):
// all 256 blocks: one full-K q|k tile -> Cqk[4096][4096] f32.
// blocks 0..127: one K-half (1664, 26 Kt) of a V-column tile -> bf16 slab Cvp[kc].
__global__ __launch_bounds__(512, 2) void k_gemm256_qkv(
    const u16* __restrict__ A, const u16* __restrict__ B,
    float* __restrict__ Cqk, u16* __restrict__ Cvp) {
  __shared__ u16 As[2 * 16384];
  __shared__ u16 Bs[2 * 16384];
  const int bid = (int)blockIdx.x;
  const int xcd = bid & 7, rest = bid >> 3;
  const int wg = xcd * 32 + rest;          // nwg=256 -> qq=32, rr=0
  const int m0 = (wg >> 4) << 8;
  const int n0 = (wg & 15) << 8;
  gemm256_run<0>(A, B, 3328, 52, m0, n0, Cqk, 4096, n0, As, Bs);
  if (bid >= 128) return;
  __syncthreads();  // all waves done reading LDS before round2 restages
  const int m  = bid & 15;
  const int nv = (bid >> 4) & 3;
  const int kc = bid >> 6;                                  // 0 or 1
  const u16* At = A + kc * 1664;
  const u16* Bt = B + (size_t)4096 * 3328 + kc * 1664;      // V rows of wwq
  gemm256_run<1>(At, Bt, 3328, 26, m * 256, nv * 256,
                 Cvp + (size_t)kc * 4096 * 1024, 1024, nv * 256, As, Bs);
}

// ---------------- RoPE cos/sin table (+ attn work-queue counter reset) ----------------
__global__ void k_rope_tab(const int* __restrict__ pos_ids, float* __restrict__ tab,
                           int* __restrict__ ctr) {
  if (blockIdx.x == 0 && threadIdx.x == 0) *ctr = 0;
  const int t = threadIdx.x;
  const int r = blockIdx.x * 4 + t / 48;
  const int j = t % 48;
  const float pos = (float)pos_ids[r];
  float invf = powf(10000.0f, -(float)j * (1.0f / 48.0f));
  float e = pos * invf;
  tab[(size_t)r * 96 + j]      = cosf(e);
  tab[(size_t)r * 96 + 48 + j] = sinf(e);
}

// ---------------- merged RoPE-split (y<32, reads Cqk) + V-transpose (y==32, sums Cvp) ----------------
__global__ void k_rope_v(const float* __restrict__ qk, const u16* __restrict__ vp,
                         const float* __restrict__ tab,
                         u16* __restrict__ qb, u16* __restrict__ kb, u16* __restrict__ vtg) {
  const int y = blockIdx.y;
  const int d = threadIdx.x;
  if (y < 32) {
    const int r  = blockIdx.x;
    const int hh = y;
    const float* src;
    if (hh < 24) src = qk + (size_t)r * 4096 + hh * 128;
    else         src = qk + (size_t)r * 4096 + 3072 + (hh - 24) * 128;
    float x = src[d];
    float outv;
    if (d >= 96) {
      outv = x;
    } else {
      int j = (d < 48) ? d : d - 48;
      float c  = tab[(size_t)r * 96 + j];
      float sn = tab[(size_t)r * 96 + 48 + j];
      if (d < 48) outv = x * c - src[d + 48] * sn;
      else        outv = x * c + src[d - 48] * sn;
    }
    u16 o = f2bf(outv);
    if (hh < 24) qb[((size_t)r * 24 + hh) * 128 + d] = o;
    else         kb[((size_t)r * 8 + (hh - 24)) * 128 + d] = o;
  } else {
    const int bk = blockIdx.x >> 8;
    const int kg = blockIdx.x & 255;
    const int b = bk >> 3, kvh = bk & 7;
    const u16* s0 = vp + (size_t)(b * 2048 + kg * 8) * 1024 + kvh * 128 + d;
    const u16* s1 = s0 + (size_t)4096 * 1024;
    u16x8 pack;
#pragma unroll
    for (int t = 0; t < 8; ++t)
      pack[t] = f2bf(bf2f(s0[(size_t)t * 1024]) + bf2f(s1[(size_t)t * 1024]));
    *(u16x8*)(vtg + ((size_t)bk * 128 + d) * 2048 + kg * 8) = pack;
  }
}

// ---------------- MFMA flash attention, 32x32, persistent work-queue (R8, frozen) ----------------
#define NJOBS 768

__global__ __launch_bounds__(256) void k_attn_mfma(
    const u16* __restrict__ qb, const u16* __restrict__ kb, const u16* __restrict__ vtg,
    u16* __restrict__ attnw, int* __restrict__ ctr) {
  __shared__ u16 Ks0[8192], Ks1[8192];
  __shared__ u16 Vt0[8192], Vt1[8192];
  __shared__ int s_job;

  const int tid  = threadIdx.x;
  const int lane = tid & 63;
  const int w    = tid >> 6;
  const int l31  = lane & 31;
  const int hi   = lane >> 5;
  const int r7   = lane & 7;
  const float C1 = 0.08838834764831845f * 1.4426950408889634f;

  for (;;) {
    if (tid == 0) s_job = atomicAdd(ctr, 1);
    __syncthreads();
    const int j = s_job;
    if (j >= NJOBS) return;

    const int qt  = 15 - (j / 48);
    const int bh  = j % 48;
    const int b   = bh / 24;
    const int h   = bh % 24;
    const int kvh = h / 3;
    const int q0  = qt * 128;
    const int qrow = q0 + w * 32 + l31;

    const u16* qrb = qb + (((size_t)(b * 2048 + qrow)) * 24 + h) * 128;
    bf16x8 qf[8];
#pragma unroll
    for (int kk = 0; kk < 8; ++kk) qf[kk] = *(const bf16x8*)(qrb + kk * 16 + hi * 8);

    const u16* kbbase = kb + ((size_t)(b * 2048) * 8 + kvh) * 128;
    const u16* vtbase = vtg + (size_t)(b * 8 + kvh) * 128 * 2048;

    f32x16 o32[4] = {};
    float m_st = -INFINITY, l_st = 0.f;
    const int ntile = 2 * qt + 2;

#define STAGE_K(Kd, KB0)                                                        \
  { _Pragma("unroll") for (int i = 0; i < 4; ++i) {                             \
      const int c = w * 4 + i;                                                  \
      const int rowk = 4 * c + (lane >> 4);                                     \
      gload_lds16(kbbase + (size_t)((KB0) + rowk) * 1024 +                      \
                      (((lane & 15) ^ (rowk & 7)) << 3),                        \
                  (Kd) + c * 512); } }
#define STAGE_V(Vd, KB0)                                                        \
  { _Pragma("unroll") for (int i = 0; i < 4; ++i) {                             \
      const int c = w * 4 + i;                                                  \
      const int rowv = 8 * c + (lane >> 3);                                     \
      gload_lds16(vtbase + (size_t)rowv * 2048 + (KB0) +                        \
                      (((lane & 7) ^ (rowv & 7)) << 3),                         \
                  (Vd) + c * 512); } }

    STAGE_K(Ks0, 0);
    STAGE_V(Vt0, 0);

    for (int t = 0; t < ntile; ++t) {
      const int kb0 = t * 64;
      const u16* Kc = (t & 1) ? Ks1 : Ks0;
      const u16* Vc = (t & 1) ? Vt1 : Vt0;

      asm volatile("s_waitcnt vmcnt(0)" ::: "memory");
      SBAR0(); HWBAR(); SBAR0();
      if (t + 1 < ntile) {
        u16* Kn = (t & 1) ? Ks0 : Ks1;
        u16* Vn = (t & 1) ? Vt0 : Vt1;
        STAGE_K(Kn, kb0 + 64);
        STAGE_V(Vn, kb0 + 64);
      }
      SBAR0();

      f32x16 s0 = {}, s1 = {};
      __builtin_amdgcn_s_setprio(1);
#pragma unroll
      for (int kk = 0; kk < 8; ++kk) {
        bf16x8 kf0 = *(const bf16x8*)&Kc[l31 * 128 + (((2 * kk + hi) ^ r7) << 3)];
        s0 = __builtin_amdgcn_mfma_f32_32x32x16_bf16(kf0, qf[kk], s0, 0, 0, 0);
        bf16x8 kf1 = *(const bf16x8*)&Kc[(32 + l31) * 128 + (((2 * kk + hi) ^ ((32 + l31) & 7)) << 3)];
        s1 = __builtin_amdgcn_mfma_f32_32x32x16_bf16(kf1, qf[kk], s1, 0, 0, 0);
      }
      __builtin_amdgcn_s_setprio(0);

      if (kb0 >= q0) {
#pragma unroll
        for (int r = 0; r < 16; ++r) {
          const int crow = (r & 3) + 8 * (r >> 2) + 4 * hi;
          if (kb0 + crow > qrow)      s0[r] = -INFINITY;
          if (kb0 + 32 + crow > qrow) s1[r] = -INFINITY;
        }
      }

      float tm[8];
#pragma unroll
      for (int r = 0; r < 8; ++r)
        tm[r] = fmaxf(fmaxf(s0[r], s0[r + 8]), fmaxf(s1[r], s1[r + 8]));
#pragma unroll
      for (int st = 4; st >= 1; st >>= 1)
#pragma unroll
        for (int r = 0; r < 4; ++r)
          if (r < st) tm[r] = fmaxf(tm[r], tm[r + st]);
      float mx = fmaxf(tm[0], __shfl_xor(tm[0], 32));

      const bool skip = __all((mx - m_st) * C1 <= 8.0f);
      if (!skip) {
        const float mnew = fmaxf(m_st, mx);
        const float alpha = fast_exp2((m_st - mnew) * C1);
        l_st *= alpha;
#pragma unroll
        for (int dt = 0; dt < 4; ++dt)
#pragma unroll
          for (int r = 0; r < 16; ++r) o32[dt][r] *= alpha;
        m_st = mnew;
      }
      const float mc = m_st * C1;
      float ts[8];
#pragma unroll
      for (int r = 0; r < 16; ++r) {
        s0[r] = fast_exp2(__builtin_fmaf(s0[r], C1, -mc));
        s1[r] = fast_exp2(__builtin_fmaf(s1[r], C1, -mc));
      }
#pragma unroll
      for (int r = 0; r < 8; ++r) ts[r] = (s0[r] + s0[r + 8]) + (s1[r] + s1[r + 8]);
#pragma unroll
      for (int st = 4; st >= 1; st >>= 1)
#pragma unroll
        for (int r = 0; r < 4; ++r)
          if (r < st) ts[r] += ts[r + st];
      l_st += ts[0] + __shfl_xor(ts[0], 32);

#pragma unroll
      for (int kt = 0; kt < 2; ++kt) {
        const f32x16& sv = kt ? s1 : s0;
        u32 pk[8];
#pragma unroll
        for (int i = 0; i < 8; ++i)
          asm("v_cvt_pk_bf16_f32 %0, %1, %2"
              : "=v"(pk[i]) : "v"(sv[2 * i]), "v"(sv[2 * i + 1]));
        u32 e0 = __shfl_xor(hi ? pk[0] : pk[2], 32);
        u32 e1 = __shfl_xor(hi ? pk[1] : pk[3], 32);
        u32 e2 = __shfl_xor(hi ? pk[4] : pk[6], 32);
        u32 e3 = __shfl_xor(hi ? pk[5] : pk[7], 32);
        u32x4 w0, w1;
        w0[0] = hi ? e0 : pk[0]; w0[1] = hi ? e1 : pk[1];
        w0[2] = hi ? pk[2] : e0; w0[3] = hi ? pk[3] : e1;
        w1[0] = hi ? e2 : pk[4]; w1[1] = hi ? e3 : pk[5];
        w1[2] = hi ? pk[6] : e2; w1[3] = hi ? pk[7] : e3;
        bf16x8 pb0 = __builtin_bit_cast(bf16x8, w0);
        bf16x8 pb1 = __builtin_bit_cast(bf16x8, w1);
        __builtin_amdgcn_s_setprio(1);
#pragma unroll
        for (int dt = 0; dt < 4; ++dt) {
          const int vrow = dt * 32 + l31;
          bf16x8 vf0 = *(const bf16x8*)&Vc[vrow * 64 + (((2 * (2 * kt) + hi) ^ (vrow & 7)) << 3)];
          o32[dt] = __builtin_amdgcn_mfma_f32_32x32x16_bf16(vf0, pb0, o32[dt], 0, 0, 0);
          bf16x8 vf1 = *(const bf16x8*)&Vc[vrow * 64 + (((2 * (2 * kt + 1) + hi) ^ (vrow & 7)) << 3)];
          o32[dt] = __builtin_amdgcn_mfma_f32_32x32x16_bf16(vf1, pb1, o32[dt], 0, 0, 0);
        }
        __builtin_amdgcn_s_setprio(0);
      }
    }

    __syncthreads();
    const float inv = 1.0f / l_st;
    u16* scr = ((w < 2) ? Ks0 : Ks1) + (w & 1) * 4096;
#pragma unroll
    for (int dt = 0; dt < 4; ++dt)
#pragma unroll
      for (int r = 0; r < 16; ++r) {
        const int d = 32 * dt + (r & 3) + 8 * (r >> 2) + 4 * hi;
        const int slot = (d >> 3) ^ (l31 & 7);
        scr[l31 * 128 + slot * 8 + (d & 7)] = f2bf(o32[dt][r] * inv);
      }
    const int q32r = lane >> 1, part = lane & 1;
    const size_t grow = ((size_t)(b * 2048 + q0 + w * 32 + q32r)) * 3328 + (size_t)h * 128;
#pragma unroll
    for (int c = 0; c < 8; ++c) {
      const int d0 = part * 64 + c * 8;
      const int s2 = (d0 >> 3) ^ (q32r & 7);
      *(u16x8*)(attnw + grow + d0) = *(const u16x8*)&scr[q32r * 128 + s2 * 8];
    }
  }
}

// ---------------- workspace layout (bytes), total 173,015,040 ----------------
#define OFF_XW    ((size_t)0)
#define OFF_WWQ   ((size_t)27262976)
#define OFF_AQKVB ((size_t)61341696)
#define OFF_WWO   ((size_t)62914560)
#define OFF_AOB   ((size_t)83361792)
#define OFF_QKV   ((size_t)84934656)               // Cqk [4096][4096] f32 = 67108864
#define OFF_CVP   (OFF_QKV + (size_t)67108864)     // Cvp [2][4096][1024] bf16 = 16777216
#define OFF_RTAB  (OFF_CVP + (size_t)16777216)     // 1572864 (true tail)
#define OFF_CTR   (OFF_RTAB + (size_t)1572864)     // 4 B
#define OFF_TA4   OFF_QKV
#define OFF_VTG   (OFF_WWQ + (size_t)8388608)      // wwq dead after k_gemm256_qkv
#define OFF_ATTNW OFF_QKV                          // Cqk dead after k_rope_v
#define OFF_TO4   (OFF_QKV + (size_t)27262976)
// qb (24 MB) / kb (8 MB) live in d_out scratch (50 MB, overwritten by the Wo GEMM)

extern "C" void kernel_launch(void* const* d_in, const int* in_sizes, int n_in,
                              void* d_out, int out_size, void* d_ws, size_t ws_size,
                              hipStream_t stream) {
  const float* x    = (const float*)d_in[0];
  const float* Wqkv = (const float*)d_in[1];
  const float* Aqkv = (const float*)d_in[2];
  const float* Bqkv = (const float*)d_in[3];
  const float* Wo   = (const float*)d_in[4];
  const float* Ao   = (const float*)d_in[5];
  const float* Bo   = (const float*)d_in[6];
  const int*   pos  = (const int*)d_in[7];
  float* out = (float*)d_out;
  char* ws = (char*)d_ws;

  u16* xw    = (u16*)(ws + OFF_XW);
  u16* wwq   = (u16*)(ws + OFF_WWQ);
  u16* aqkvb = (u16*)(ws + OFF_AQKVB);
  u16* wwo   = (u16*)(ws + OFF_WWO);
  u16* aob   = (u16*)(ws + OFF_AOB);
  float* qk  = (float*)(ws + OFF_QKV);
  u16* cvp   = (u16*)(ws + OFF_CVP);
  float* rtab = (float*)(ws + OFF_RTAB);
  int* ctr   = (int*)(ws + OFF_CTR);
  float* tA4 = (float*)(ws + OFF_TA4);
  u16* vtg   = (u16*)(ws + OFF_VTG);
  u16* attnw = (u16*)(ws + OFF_ATTNW);
  float* tO4 = (float*)(ws + OFF_TO4);
  u16* qb    = (u16*)d_out;
  u16* kb    = (u16*)((char*)d_out + 25165824);

  // 1) all casts in one launch
  k_cast_all<<<2048, 256, 0, stream>>>(x, Wqkv, Bqkv, Aqkv, Wo, Bo, Ao,
                                       xw, wwq, aqkvb, wwo, aob);

  // 2) LoRA-A: tA = x @ Aqkv^T (split-K x4) -> xw tail (scaled by 2)
  k_gemm_bt_sk<<<dim3(4, 64, 4), 256, 0, stream>>>(xw, aqkvb, tA4, 4096, 256, 3328, 3072, 768);
  k_red4_cast<<<dim3(1, 4096), 64, 0, stream>>>(tA4, xw, 32, 3328, 3072, 2.f, (size_t)4096 * 256);

  // 3) rope table + ctr reset (true-tail region, never aliases live data)
  k_rope_tab<<<dim3(1024), 192, 0, stream>>>(pos, rtab, ctr);

  // 4) qkv GEMM: q|k full-K (256 blocks) then V split-K x2 bf16 slabs (128 blocks)
  k_gemm256_qkv<<<dim3(256), 512, 0, stream>>>(xw, wwq, qk, cvp);

  // 5) rope-qk + V-transpose (high-parallelism, BW-saturating)
  k_rope_v<<<dim3(4096, 33), 128, 0, stream>>>(qk, cvp, rtab, qb, kb, vtg);

  // 6) MFMA flash attention (persistent, work-queue) -> attnw (stride 3328)
  k_attn_mfma<<<dim3(512), 256, 0, stream>>>(qb, kb, vtg, attnw, ctr);

  // 7) LoRA-A out: tO = attn @ Ao^T (split-K x4) -> attnw tail (scaled by 2)
  k_gemm_bt_sk<<<dim3(4, 64, 4), 256, 0, stream>>>(attnw, aob, tO4, 4096, 256, 3328, 3072, 768);
  k_red4_cast<<<dim3(1, 4096), 64, 0, stream>>>(tO4, attnw, 32, 3328, 3072, 2.f, (size_t)4096 * 256);

  // 8) out = [attn | 2 tO] @ [Wo | Bo]^T  (K=3328)
  k_gemm256<<<dim3((3072 / 256) * (4096 / 256)), 512, 0, stream>>>(attnw, wwo, out, 4096, 3072, 3328);
}

// Round 13
// 643.189 us; speedup vs baseline: 1.1412x; 1.0119x over previous
//
#include <hip/hip_runtime.h>

typedef unsigned short u16;
typedef unsigned int   u32;

typedef __bf16 bf16_t;
typedef bf16_t bf16x8 __attribute__((ext_vector_type(8)));
typedef float  f32x4  __attribute__((ext_vector_type(4)));
typedef float  f32x16 __attribute__((ext_vector_type(16)));
typedef u16    u16x8  __attribute__((ext_vector_type(8)));
typedef u32    u32x4  __attribute__((ext_vector_type(4)));

__device__ __forceinline__ float bf2f(u16 u) { return __uint_as_float(((u32)u) << 16); }
__device__ __forceinline__ u16 f2bf(float f) {
  u32 u = __float_as_uint(f);
  u32 r = u + 0x7fffu + ((u >> 16) & 1u);
  return (u16)(r >> 16);
}
__device__ __forceinline__ float fast_exp2(float x) { return __builtin_amdgcn_exp2f(x); }

__device__ __forceinline__ void gload_lds16(const u16* g, u16* l) {
  __builtin_amdgcn_global_load_lds(
      (const __attribute__((address_space(1))) void*)g,
      (__attribute__((address_space(3))) void*)l,
      16, 0, 0);
}

#define SBAR0() __builtin_amdgcn_sched_barrier(0)
#define HWBAR() __builtin_amdgcn_s_barrier()

// ---------------- merged cast f32 -> bf16 into concat layouts (1 launch) ----------------
__global__ void k_cast_all(const float* __restrict__ x,  const float* __restrict__ wq,
                           const float* __restrict__ bq, const float* __restrict__ aq,
                           const float* __restrict__ wo, const float* __restrict__ bo,
                           const float* __restrict__ ao,
                           u16* __restrict__ xw, u16* __restrict__ wwq, u16* __restrict__ aqkvb,
                           u16* __restrict__ wwo, u16* __restrict__ aob) {
  const int total = 5177344;
  int i = blockIdx.x * blockDim.x + threadIdx.x;
  const int stride = gridDim.x * blockDim.x;
  for (; i < total; i += stride) {
    const float* src; u16* dst; int r, c8, L, off, sL;
    if (i < 1572864)      { int loc = i;           r = loc / 384; c8 = loc - r * 384; src = x;  dst = xw;    L = 3328; off = 0;    sL = 3072; }
    else if (i < 3538944) { int loc = i - 1572864; r = loc / 384; c8 = loc - r * 384; src = wq; dst = wwq;   L = 3328; off = 0;    sL = 3072; }
    else if (i < 3702784) { int loc = i - 3538944; r = loc >> 5;  c8 = loc & 31;      src = bq; dst = wwq;   L = 3328; off = 3072; sL = 256;  }
    else if (i < 3801088) { int loc = i - 3702784; r = loc / 384; c8 = loc - r * 384; src = aq; dst = aqkvb; L = 3072; off = 0;    sL = 3072; }
    else if (i < 4980736) { int loc = i - 3801088; r = loc / 384; c8 = loc - r * 384; src = wo; dst = wwo;   L = 3328; off = 0;    sL = 3072; }
    else if (i < 5079040) { int loc = i - 4980736; r = loc >> 5;  c8 = loc & 31;      src = bo; dst = wwo;   L = 3328; off = 3072; sL = 256;  }
    else                  { int loc = i - 5079040; r = loc / 384; c8 = loc - r * 384; src = ao; dst = aob;   L = 3072; off = 0;    sL = 3072; }
    const f32x4* p = (const f32x4*)(src + (size_t)r * sL + c8 * 8);
    f32x4 a = p[0], b2 = p[1];
    u16x8 o;
    o[0] = f2bf(a[0]);  o[1] = f2bf(a[1]);  o[2] = f2bf(a[2]);  o[3] = f2bf(a[3]);
    o[4] = f2bf(b2[0]); o[5] = f2bf(b2[1]); o[6] = f2bf(b2[2]); o[7] = f2bf(b2[3]);
    *(u16x8*)(dst + (size_t)r * L + off + c8 * 8) = o;
  }
}

// ---------------- reduce 4 f32 slabs + scale + strided cast to bf16 ----------------
__global__ void k_red4_cast(const float* __restrict__ t4, u16* __restrict__ out,
                            int C8, int L, int off, float scale, size_t plane) {
  const int r  = blockIdx.y;
  const int c8 = blockIdx.x * 64 + threadIdx.x;
  if (c8 >= C8) return;
  size_t base = (size_t)r * (C8 * 8) + c8 * 8;
  float s[8];
#pragma unroll
  for (int j = 0; j < 8; ++j) s[j] = 0.f;
#pragma unroll
  for (int p = 0; p < 4; ++p) {
    const f32x4* q = (const f32x4*)(t4 + p * plane + base);
    f32x4 a = q[0], b = q[1];
    s[0] += a[0]; s[1] += a[1]; s[2] += a[2]; s[3] += a[3];
    s[4] += b[0]; s[5] += b[1]; s[6] += b[2]; s[7] += b[3];
  }
  u16x8 o;
#pragma unroll
  for (int j = 0; j < 8; ++j) o[j] = f2bf(s[j] * scale);
  *(u16x8*)(out + (size_t)r * L + off + c8 * 8) = o;
}

// ---------------- small GEMM (64x64 tile), split-K slabs ----------------
__global__ __launch_bounds__(256) void k_gemm_bt_sk(
    const u16* __restrict__ A, const u16* __restrict__ B, float* __restrict__ C,
    int M, int N, int lda, int ldb, int kc) {
  __shared__ u16 As[64][64 + 8];
  __shared__ u16 Bs[64][64 + 8];
  const int tid   = threadIdx.x;
  const int lane  = tid & 63;
  const int w     = tid >> 6;
  const int wm    = (w >> 1) * 32;
  const int wn    = (w & 1) * 32;
  const int row16 = lane & 15;
  const int quad  = lane >> 4;
  const int m0 = blockIdx.y * 64;
  const int n0 = blockIdx.x * 64;
  const int ldr = tid >> 2;
  const int ldc = (tid & 3) * 16;
  const int z   = blockIdx.z;
  float* Cz = C + (size_t)z * M * N;
  const int kbeg = z * kc, kend = kbeg + kc;

  f32x4 acc[2][2] = {};

  for (int k0 = kbeg; k0 < kend; k0 += 64) {
    const u16* ga = A + (size_t)(m0 + ldr) * lda + (k0 + ldc);
    const u16* gb = B + (size_t)(n0 + ldr) * ldb + (k0 + ldc);
    u16x8 a0 = *(const u16x8*)ga;
    u16x8 a1 = *(const u16x8*)(ga + 8);
    u16x8 b0 = *(const u16x8*)gb;
    u16x8 b1 = *(const u16x8*)(gb + 8);
    __syncthreads();
    *(u16x8*)&As[ldr][ldc]     = a0;
    *(u16x8*)&As[ldr][ldc + 8] = a1;
    *(u16x8*)&Bs[ldr][ldc]     = b0;
    *(u16x8*)&Bs[ldr][ldc + 8] = b1;
    __syncthreads();
#pragma unroll
    for (int kk = 0; kk < 64; kk += 32) {
      bf16x8 af0 = *(const bf16x8*)&As[wm + row16][kk + quad * 8];
      bf16x8 af1 = *(const bf16x8*)&As[wm + 16 + row16][kk + quad * 8];
      bf16x8 bg0 = *(const bf16x8*)&Bs[wn + row16][kk + quad * 8];
      bf16x8 bg1 = *(const bf16x8*)&Bs[wn + 16 + row16][kk + quad * 8];
      acc[0][0] = __builtin_amdgcn_mfma_f32_16x16x32_bf16(af0, bg0, acc[0][0], 0, 0, 0);
      acc[0][1] = __builtin_amdgcn_mfma_f32_16x16x32_bf16(af0, bg1, acc[0][1], 0, 0, 0);
      acc[1][0] = __builtin_amdgcn_mfma_f32_16x16x32_bf16(af1, bg0, acc[1][0], 0, 0, 0);
      acc[1][1] = __builtin_amdgcn_mfma_f32_16x16x32_bf16(af1, bg1, acc[1][1], 0, 0, 0);
    }
  }
#pragma unroll
  for (int tm = 0; tm < 2; ++tm)
#pragma unroll
    for (int tn = 0; tn < 2; ++tn) {
      int gm = m0 + wm + tm * 16 + quad * 4;
      int gn = n0 + wn + tn * 16 + row16;
#pragma unroll
      for (int r = 0; r < 4; ++r)
        Cz[(size_t)(gm + r) * N + gn] = acc[tm][tn][r];
    }
}

// ================= 256x256 8-phase GEMM core, shallow pipeline (R10-verified) =================
// One stage_half per phase (spread staging — measured faster than clustered deep version),
// boundary vmcnt(2). S = row stride of A/B (u16); K-extent via nt (A/B may be k-offset).
__device__ __forceinline__ void stage_half(
    int H, int nt4,
    const u16* __restrict__ A, const u16* __restrict__ B, int S,
    int m0, int n0, u16* AsB, u16* BsB,
    int w, int rowin, int colsw) {
  if (H >= nt4) return;
  const int t = H >> 2, slot = H & 3;
  const int half = slot & 1;
  const u16* G = (slot < 2) ? A : B;
  const int r0 = (slot < 2) ? m0 : n0;
  u16* lds = ((slot < 2) ? AsB : BsB) + (t & 1) * 16384 + half * 8192;
  const int k0 = t * 64;
#pragma unroll
  for (int i = 0; i < 2; ++i) {
    const int chunk = w * 2 + i;
    const int row = half * 128 + chunk * 8 + rowin;
    gload_lds16(G + (size_t)(r0 + row) * S + k0 + colsw, lds + chunk * 512);
  }
}

__device__ __forceinline__ bf16x8 frag_ld(const u16* base, int row, int c16) {
  return *(const bf16x8*)(base + row * 64 + ((c16 ^ (row & 7)) << 3));
}

template <int RB>
__device__ __forceinline__ void gemm256_group(
    int k, int nt,
    const u16* __restrict__ A, const u16* __restrict__ B, int S,
    int m0, int n0, u16* AsB, u16* BsB,
    int wr, int wc, int row16, int quad, int w, int rowin, int colsw,
    f32x4 (&acc)[8][4]) {
  const u16* Ab = AsB + RB * 16384;
  const u16* Bb = BsB + RB * 16384;
  const int nt4 = nt * 4;
  bf16x8 a0[4][2], a1[4][2], b0[2][2], b1[2][2];

#pragma unroll
  for (int mf = 0; mf < 4; ++mf)
#pragma unroll
    for (int kk = 0; kk < 2; ++kk)
      a0[mf][kk] = frag_ld(Ab, wr * 128 + mf * 16 + row16, kk * 4 + quad);
#pragma unroll
  for (int nf = 0; nf < 2; ++nf)
#pragma unroll
    for (int kk = 0; kk < 2; ++kk)
      b0[nf][kk] = frag_ld(Bb, wc * 64 + nf * 16 + row16, kk * 4 + quad);
  stage_half(4 * k + 5, nt4, A, B, S, m0, n0, AsB, BsB, w, rowin, colsw);
  SBAR0(); HWBAR(); SBAR0();
  __builtin_amdgcn_s_setprio(1);
#pragma unroll
  for (int mf = 0; mf < 4; ++mf)
#pragma unroll
    for (int nf = 0; nf < 2; ++nf)
#pragma unroll
      for (int kk = 0; kk < 2; ++kk)
        acc[mf][nf] = __builtin_amdgcn_mfma_f32_16x16x32_bf16(a0[mf][kk], b0[nf][kk], acc[mf][nf], 0, 0, 0);
  __builtin_amdgcn_s_setprio(0);
  SBAR0(); HWBAR(); SBAR0();

#pragma unroll
  for (int nf = 0; nf < 2; ++nf)
#pragma unroll
    for (int kk = 0; kk < 2; ++kk)
      b1[nf][kk] = frag_ld(Bb, wc * 64 + 32 + nf * 16 + row16, kk * 4 + quad);
  stage_half(4 * k + 6, nt4, A, B, S, m0, n0, AsB, BsB, w, rowin, colsw);
  SBAR0(); HWBAR(); SBAR0();
  __builtin_amdgcn_s_setprio(1);
#pragma unroll
  for (int mf = 0; mf < 4; ++mf)
#pragma unroll
    for (int nf = 0; nf < 2; ++nf)
#pragma unroll
      for (int kk = 0; kk < 2; ++kk)
        acc[mf][2 + nf] = __builtin_amdgcn_mfma_f32_16x16x32_bf16(a0[mf][kk], b1[nf][kk], acc[mf][2 + nf], 0, 0, 0);
  __builtin_amdgcn_s_setprio(0);
  SBAR0(); HWBAR(); SBAR0();

#pragma unroll
  for (int mf = 0; mf < 4; ++mf)
#pragma unroll
    for (int kk = 0; kk < 2; ++kk)
      a1[mf][kk] = frag_ld(Ab, wr * 128 + 64 + mf * 16 + row16, kk * 4 + quad);
  stage_half(4 * k + 7, nt4, A, B, S, m0, n0, AsB, BsB, w, rowin, colsw);
  SBAR0(); HWBAR(); SBAR0();
  __builtin_amdgcn_s_setprio(1);
#pragma unroll
  for (int mf = 0; mf < 4; ++mf)
#pragma unroll
    for (int nf = 0; nf < 2; ++nf)
#pragma unroll
      for (int kk = 0; kk < 2; ++kk)
        acc[4 + mf][nf] = __builtin_amdgcn_mfma_f32_16x16x32_bf16(a1[mf][kk], b0[nf][kk], acc[4 + mf][nf], 0, 0, 0);
  __builtin_amdgcn_s_setprio(0);
  SBAR0(); HWBAR(); SBAR0();

  stage_half(4 * k + 8, nt4, A, B, S, m0, n0, AsB, BsB, w, rowin, colsw);
  SBAR0();
  if (k < nt - 2) { asm volatile("s_waitcnt vmcnt(2)" ::: "memory"); }
  else            { asm volatile("s_waitcnt vmcnt(0)" ::: "memory"); }
  HWBAR(); SBAR0();
  __builtin_amdgcn_s_setprio(1);
#pragma unroll
  for (int mf = 0; mf < 4; ++mf)
#pragma unroll
    for (int nf = 0; nf < 2; ++nf)
#pragma unroll
      for (int kk = 0; kk < 2; ++kk)
        acc[4 + mf][2 + nf] = __builtin_amdgcn_mfma_f32_16x16x32_bf16(a1[mf][kk], b1[nf][kk], acc[4 + mf][2 + nf], 0, 0, 0);
  __builtin_amdgcn_s_setprio(0);
  SBAR0(); HWBAR(); SBAR0();
}

// Full 256x256xK run. BF16OUT=1: store bf16 partials (split-K slab); else f32 stores.
template <int BF16OUT>
__device__ __forceinline__ void gemm256_run(
    const u16* __restrict__ A, const u16* __restrict__ B, int S, int nt,
    int m0, int n0, void* __restrict__ Cp, int ldc, int cn0,
    u16* As, u16* Bs) {
  const int tid   = threadIdx.x;
  const int lane  = tid & 63;
  const int w     = tid >> 6;
  const int wr    = w >> 2;
  const int wc    = w & 3;
  const int row16 = lane & 15;
  const int quad  = lane >> 4;
  const int rowin = lane >> 3;
  const int colsw = ((lane & 7) ^ (lane >> 3)) << 3;

  f32x4 acc[8][4] = {};

#pragma unroll
  for (int H = 0; H < 5; ++H)
    stage_half(H, nt * 4, A, B, S, m0, n0, As, Bs, w, rowin, colsw);
  asm volatile("s_waitcnt vmcnt(2)" ::: "memory");
  HWBAR(); SBAR0();

  int k = 0;
  for (; k + 1 < nt; k += 2) {
    gemm256_group<0>(k,     nt, A, B, S, m0, n0, As, Bs, wr, wc, row16, quad, w, rowin, colsw, acc);
    gemm256_group<1>(k + 1, nt, A, B, S, m0, n0, As, Bs, wr, wc, row16, quad, w, rowin, colsw, acc);
  }
  if (k < nt)
    gemm256_group<0>(k, nt, A, B, S, m0, n0, As, Bs, wr, wc, row16, quad, w, rowin, colsw, acc);

#pragma unroll
  for (int mi = 0; mi < 8; ++mi) {
    const int gm = m0 + wr * 128 + mi * 16 + quad * 4;
#pragma unroll
    for (int nj = 0; nj < 4; ++nj) {
      const int gn = cn0 + wc * 64 + nj * 16 + row16;
#pragma unroll
      for (int r = 0; r < 4; ++r) {
        if (BF16OUT) ((u16*)Cp)[(size_t)(gm + r) * ldc + gn] = f2bf(acc[mi][nj][r]);
        else         ((float*)Cp)[(size_t)(gm + r) * ldc + gn] = acc[mi][nj][r];
      }
    }
  }
}

// generic wrapper (Wo GEMM): C(MxN) = A @ B^T, K = stride = extent
__global__ __launch_bounds__(512, 2) void k_gemm256(
    const u16* __restrict__ A, const u16* __restrict__ B, float* __restrict__ C,
    int M, int N, int K) {
  __shared__ u16 As[2 * 16384];
  __shared__ u16 Bs[2 * 16384];
  const int nwg = (int)gridDim.x;
  const int bid = (int)blockIdx.x;
  const int xcd = bid & 7, rest = bid >> 3;
  const int qq = nwg >> 3, rr = nwg & 7;
  const int wg = (xcd < rr ? xcd * (qq + 1) : rr * (qq + 1) + (xcd - rr) * qq) + rest;
  const int nbx = N >> 8;
  const int m0 = (wg / nbx) << 8;
  const int n0 = (wg % nbx) << 8;
  gemm256_run<0>(A, B, K, K >> 6, m0, n0, C, N, n0, As, Bs);
}

// qkv GEMM, fully balanced (R13): all 256 blocks do one full-K q|k tile (52 Kt)
// then one quarter-K V-chunk (13 Kt) -> 4 bf16 partial slabs (2 in ws, 2 in d_out tail).
// Critical path 65 Kt/block, uniform across the grid. No atomics.
__global__ __launch_bounds__(512, 2) void k_gemm256_qkv(
    const u16* __restrict__ A, const u16* __restrict__ B,
    float* __restrict__ Cqk, u16* __restrict__ Cvp0, u16* __restrict__ Cvp1) {
  __shared__ u16 As[2 * 16384];
  __shared__ u16 Bs[2 * 16384];
  const int bid = (int)blockIdx.x;
  const int xcd = bid & 7, rest = bid >> 3;
  const int wg = xcd * 32 + rest;          // nwg=256 -> qq=32, rr=0
  const int m0 = (wg >> 4) << 8;
  const int n0 = (wg & 15) << 8;
  gemm256_run<0>(A, B, 3328, 52, m0, n0, Cqk, 4096, n0, As, Bs);
  __syncthreads();  // all waves done reading LDS before round2 restages
  const int m  = bid & 15;
  const int nv = (bid >> 4) & 3;
  const int kc = bid >> 6;                                  // 0..3
  const u16* At = A + kc * 832;
  const u16* Bt = B + (size_t)4096 * 3328 + kc * 832;       // V rows of wwq
  u16* slab = (kc < 2) ? (Cvp0 + (size_t)kc * 4096 * 1024)
                       : (Cvp1 + (size_t)(kc - 2) * 4096 * 1024);
  gemm256_run<1>(At, Bt, 3328, 13, m * 256, nv * 256, slab, 1024, nv * 256, As, Bs);
}

// ---------------- RoPE cos/sin table (+ attn work-queue counter reset) ----------------
__global__ void k_rope_tab(const int* __restrict__ pos_ids, float* __restrict__ tab,
                           int* __restrict__ ctr) {
  if (blockIdx.x == 0 && threadIdx.x == 0) *ctr = 0;
  const int t = threadIdx.x;
  const int r = blockIdx.x * 4 + t / 48;
  const int j = t % 48;
  const float pos = (float)pos_ids[r];
  float invf = powf(10000.0f, -(float)j * (1.0f / 48.0f));
  float e = pos * invf;
  tab[(size_t)r * 96 + j]      = cosf(e);
  tab[(size_t)r * 96 + 48 + j] = sinf(e);
}

// ---------------- merged RoPE-split (y<32, reads Cqk) + V-transpose (y==32, sums 4 slabs) ----------------
__global__ void k_rope_v(const float* __restrict__ qk,
                         const u16* __restrict__ vp0, const u16* __restrict__ vp1,
                         const float* __restrict__ tab,
                         u16* __restrict__ qb, u16* __restrict__ kb, u16* __restrict__ vtg) {
  const int y = blockIdx.y;
  const int d = threadIdx.x;
  if (y < 32) {
    const int r  = blockIdx.x;
    const int hh = y;
    const float* src;
    if (hh < 24) src = qk + (size_t)r * 4096 + hh * 128;
    else         src = qk + (size_t)r * 4096 + 3072 + (hh - 24) * 128;
    float x = src[d];
    float outv;
    if (d >= 96) {
      outv = x;
    } else {
      int j = (d < 48) ? d : d - 48;
      float c  = tab[(size_t)r * 96 + j];
      float sn = tab[(size_t)r * 96 + 48 + j];
      if (d < 48) outv = x * c - src[d + 48] * sn;
      else        outv = x * c + src[d - 48] * sn;
    }
    u16 o = f2bf(outv);
    if (hh < 24) qb[((size_t)r * 24 + hh) * 128 + d] = o;
    else         kb[((size_t)r * 8 + (hh - 24)) * 128 + d] = o;
  } else {
    const int bk = blockIdx.x >> 8;
    const int kg = blockIdx.x & 255;
    const int b = bk >> 3, kvh = bk & 7;
    const size_t base = (size_t)(b * 2048 + kg * 8) * 1024 + kvh * 128 + d;
    const u16* s0 = vp0 + base;
    const u16* s1 = vp0 + (size_t)4096 * 1024 + base;
    const u16* s2 = vp1 + base;
    const u16* s3 = vp1 + (size_t)4096 * 1024 + base;
    u16x8 pack;
#pragma unroll
    for (int t = 0; t < 8; ++t) {
      const size_t o = (size_t)t * 1024;
      pack[t] = f2bf((bf2f(s0[o]) + bf2f(s1[o])) + (bf2f(s2[o]) + bf2f(s3[o])));
    }
    *(u16x8*)(vtg + ((size_t)bk * 128 + d) * 2048 + kg * 8) = pack;
  }
}

// ---------------- MFMA flash attention, 32x32, persistent work-queue (R8, frozen) ----------------
#define NJOBS 768

__global__ __launch_bounds__(256) void k_attn_mfma(
    const u16* __restrict__ qb, const u16* __restrict__ kb, const u16* __restrict__ vtg,
    u16* __restrict__ attnw, int* __restrict__ ctr) {
  __shared__ u16 Ks0[8192], Ks1[8192];
  __shared__ u16 Vt0[8192], Vt1[8192];
  __shared__ int s_job;

  const int tid  = threadIdx.x;
  const int lane = tid & 63;
  const int w    = tid >> 6;
  const int l31  = lane & 31;
  const int hi   = lane >> 5;
  const int r7   = lane & 7;
  const float C1 = 0.08838834764831845f * 1.4426950408889634f;

  for (;;) {
    if (tid == 0) s_job = atomicAdd(ctr, 1);
    __syncthreads();
    const int j = s_job;
    if (j >= NJOBS) return;

    const int qt  = 15 - (j / 48);
    const int bh  = j % 48;
    const int b   = bh / 24;
    const int h   = bh % 24;
    const int kvh = h / 3;
    const int q0  = qt * 128;
    const int qrow = q0 + w * 32 + l31;

    const u16* qrb = qb + (((size_t)(b * 2048 + qrow)) * 24 + h) * 128;
    bf16x8 qf[8];
#pragma unroll
    for (int kk = 0; kk < 8; ++kk) qf[kk] = *(const bf16x8*)(qrb + kk * 16 + hi * 8);

    const u16* kbbase = kb + ((size_t)(b * 2048) * 8 + kvh) * 128;
    const u16* vtbase = vtg + (size_t)(b * 8 + kvh) * 128 * 2048;

    f32x16 o32[4] = {};
    float m_st = -INFINITY, l_st = 0.f;
    const int ntile = 2 * qt + 2;

#define STAGE_K(Kd, KB0)                                                        \
  { _Pragma("unroll") for (int i = 0; i < 4; ++i) {                             \
      const int c = w * 4 + i;                                                  \
      const int rowk = 4 * c + (lane >> 4);                                     \
      gload_lds16(kbbase + (size_t)((KB0) + rowk) * 1024 +                      \
                      (((lane & 15) ^ (rowk & 7)) << 3),                        \
                  (Kd) + c * 512); } }
#define STAGE_V(Vd, KB0)                                                        \
  { _Pragma("unroll") for (int i = 0; i < 4; ++i) {                             \
      const int c = w * 4 + i;                                                  \
      const int rowv = 8 * c + (lane >> 3);                                     \
      gload_lds16(vtbase + (size_t)rowv * 2048 + (KB0) +                        \
                      (((lane & 7) ^ (rowv & 7)) << 3),                         \
                  (Vd) + c * 512); } }

    STAGE_K(Ks0, 0);
    STAGE_V(Vt0, 0);

    for (int t = 0; t < ntile; ++t) {
      const int kb0 = t * 64;
      const u16* Kc = (t & 1) ? Ks1 : Ks0;
      const u16* Vc = (t & 1) ? Vt1 : Vt0;

      asm volatile("s_waitcnt vmcnt(0)" ::: "memory");
      SBAR0(); HWBAR(); SBAR0();
      if (t + 1 < ntile) {
        u16* Kn = (t & 1) ? Ks0 : Ks1;
        u16* Vn = (t & 1) ? Vt0 : Vt1;
        STAGE_K(Kn, kb0 + 64);
        STAGE_V(Vn, kb0 + 64);
      }
      SBAR0();

      f32x16 s0 = {}, s1 = {};
      __builtin_amdgcn_s_setprio(1);
#pragma unroll
      for (int kk = 0; kk < 8; ++kk) {
        bf16x8 kf0 = *(const bf16x8*)&Kc[l31 * 128 + (((2 * kk + hi) ^ r7) << 3)];
        s0 = __builtin_amdgcn_mfma_f32_32x32x16_bf16(kf0, qf[kk], s0, 0, 0, 0);
        bf16x8 kf1 = *(const bf16x8*)&Kc[(32 + l31) * 128 + (((2 * kk + hi) ^ ((32 + l31) & 7)) << 3)];
        s1 = __builtin_amdgcn_mfma_f32_32x32x16_bf16(kf1, qf[kk], s1, 0, 0, 0);
      }
      __builtin_amdgcn_s_setprio(0);

      if (kb0 >= q0) {
#pragma unroll
        for (int r = 0; r < 16; ++r) {
          const int crow = (r & 3) + 8 * (r >> 2) + 4 * hi;
          if (kb0 + crow > qrow)      s0[r] = -INFINITY;
          if (kb0 + 32 + crow > qrow) s1[r] = -INFINITY;
        }
      }

      float tm[8];
#pragma unroll
      for (int r = 0; r < 8; ++r)
        tm[r] = fmaxf(fmaxf(s0[r], s0[r + 8]), fmaxf(s1[r], s1[r + 8]));
#pragma unroll
      for (int st = 4; st >= 1; st >>= 1)
#pragma unroll
        for (int r = 0; r < 4; ++r)
          if (r < st) tm[r] = fmaxf(tm[r], tm[r + st]);
      float mx = fmaxf(tm[0], __shfl_xor(tm[0], 32));

      const bool skip = __all((mx - m_st) * C1 <= 8.0f);
      if (!skip) {
        const float mnew = fmaxf(m_st, mx);
        const float alpha = fast_exp2((m_st - mnew) * C1);
        l_st *= alpha;
#pragma unroll
        for (int dt = 0; dt < 4; ++dt)
#pragma unroll
          for (int r = 0; r < 16; ++r) o32[dt][r] *= alpha;
        m_st = mnew;
      }
      const float mc = m_st * C1;
      float ts[8];
#pragma unroll
      for (int r = 0; r < 16; ++r) {
        s0[r] = fast_exp2(__builtin_fmaf(s0[r], C1, -mc));
        s1[r] = fast_exp2(__builtin_fmaf(s1[r], C1, -mc));
      }
#pragma unroll
      for (int r = 0; r < 8; ++r) ts[r] = (s0[r] + s0[r + 8]) + (s1[r] + s1[r + 8]);
#pragma unroll
      for (int st = 4; st >= 1; st >>= 1)
#pragma unroll
        for (int r = 0; r < 4; ++r)
          if (r < st) ts[r] += ts[r + st];
      l_st += ts[0] + __shfl_xor(ts[0], 32);

#pragma unroll
      for (int kt = 0; kt < 2; ++kt) {
        const f32x16& sv = kt ? s1 : s0;
        u32 pk[8];
#pragma unroll
        for (int i = 0; i < 8; ++i)
          asm("v_cvt_pk_bf16_f32 %0, %1, %2"
              : "=v"(pk[i]) : "v"(sv[2 * i]), "v"(sv[2 * i + 1]));
        u32 e0 = __shfl_xor(hi ? pk[0] : pk[2], 32);
        u32 e1 = __shfl_xor(hi ? pk[1] : pk[3], 32);
        u32 e2 = __shfl_xor(hi ? pk[4] : pk[6], 32);
        u32 e3 = __shfl_xor(hi ? pk[5] : pk[7], 32);
        u32x4 w0, w1;
        w0[0] = hi ? e0 : pk[0]; w0[1] = hi ? e1 : pk[1];
        w0[2] = hi ? pk[2] : e0; w0[3] = hi ? pk[3] : e1;
        w1[0] = hi ? e2 : pk[4]; w1[1] = hi ? e3 : pk[5];
        w1[2] = hi ? pk[6] : e2; w1[3] = hi ? pk[7] : e3;
        bf16x8 pb0 = __builtin_bit_cast(bf16x8, w0);
        bf16x8 pb1 = __builtin_bit_cast(bf16x8, w1);
        __builtin_amdgcn_s_setprio(1);
#pragma unroll
        for (int dt = 0; dt < 4; ++dt) {
          const int vrow = dt * 32 + l31;
          bf16x8 vf0 = *(const bf16x8*)&Vc[vrow * 64 + (((2 * (2 * kt) + hi) ^ (vrow & 7)) << 3)];
          o32[dt] = __builtin_amdgcn_mfma_f32_32x32x16_bf16(vf0, pb0, o32[dt], 0, 0, 0);
          bf16x8 vf1 = *(const bf16x8*)&Vc[vrow * 64 + (((2 * (2 * kt + 1) + hi) ^ (vrow & 7)) << 3)];
          o32[dt] = __builtin_amdgcn_mfma_f32_32x32x16_bf16(vf1, pb1, o32[dt], 0, 0, 0);
        }
        __builtin_amdgcn_s_setprio(0);
      }
    }

    __syncthreads();
    const float inv = 1.0f / l_st;
    u16* scr = ((w < 2) ? Ks0 : Ks1) + (w & 1) * 4096;
#pragma unroll
    for (int dt = 0; dt < 4; ++dt)
#pragma unroll
      for (int r = 0; r < 16; ++r) {
        const int d = 32 * dt + (r & 3) + 8 * (r >> 2) + 4 * hi;
        const int slot = (d >> 3) ^ (l31 & 7);
        scr[l31 * 128 + slot * 8 + (d & 7)] = f2bf(o32[dt][r] * inv);
      }
    const int q32r = lane >> 1, part = lane & 1;
    const size_t grow = ((size_t)(b * 2048 + q0 + w * 32 + q32r)) * 3328 + (size_t)h * 128;
#pragma unroll
    for (int c = 0; c < 8; ++c) {
      const int d0 = part * 64 + c * 8;
      const int s2 = (d0 >> 3) ^ (q32r & 7);
      *(u16x8*)(attnw + grow + d0) = *(const u16x8*)&scr[q32r * 128 + s2 * 8];
    }
  }
}

// ---------------- workspace layout (bytes), total 173,015,040 ----------------
#define OFF_XW    ((size_t)0)
#define OFF_WWQ   ((size_t)27262976)
#define OFF_AQKVB ((size_t)61341696)
#define OFF_WWO   ((size_t)62914560)
#define OFF_AOB   ((size_t)83361792)
#define OFF_QKV   ((size_t)84934656)               // Cqk [4096][4096] f32 = 67108864
#define OFF_CVP   (OFF_QKV + (size_t)67108864)     // Cvp slabs kc=0,1: [2][4096][1024] bf16
#define OFF_RTAB  (OFF_CVP + (size_t)16777216)     // 1572864 (true tail)
#define OFF_CTR   (OFF_RTAB + (size_t)1572864)     // 4 B
#define OFF_TA4   OFF_QKV
#define OFF_VTG   (OFF_WWQ + (size_t)8388608)      // wwq dead after k_gemm256_qkv
#define OFF_ATTNW OFF_QKV                          // Cqk dead after k_rope_v
#define OFF_TO4   (OFF_QKV + (size_t)27262976)
// d_out scratch (50,331,648 B, overwritten by the Wo GEMM):
//   qb [0 .. 25165824), kb [25165824 .. 33554432),
//   Cvp slabs kc=2,3 [33554432 .. 50331648)

extern "C" void kernel_launch(void* const* d_in, const int* in_sizes, int n_in,
                              void* d_out, int out_size, void* d_ws, size_t ws_size,
                              hipStream_t stream) {
  const float* x    = (const float*)d_in[0];
  const float* Wqkv = (const float*)d_in[1];
  const float* Aqkv = (const float*)d_in[2];
  const float* Bqkv = (const float*)d_in[3];
  const float* Wo   = (const float*)d_in[4];
  const float* Ao   = (const float*)d_in[5];
  const float* Bo   = (const float*)d_in[6];
  const int*   pos  = (const int*)d_in[7];
  float* out = (float*)d_out;
  char* ws = (char*)d_ws;

  u16* xw    = (u16*)(ws + OFF_XW);
  u16* wwq   = (u16*)(ws + OFF_WWQ);
  u16* aqkvb = (u16*)(ws + OFF_AQKVB);
  u16* wwo   = (u16*)(ws + OFF_WWO);
  u16* aob   = (u16*)(ws + OFF_AOB);
  float* qk  = (float*)(ws + OFF_QKV);
  u16* cvp0  = (u16*)(ws + OFF_CVP);
  float* rtab = (float*)(ws + OFF_RTAB);
  int* ctr   = (int*)(ws + OFF_CTR);
  float* tA4 = (float*)(ws + OFF_TA4);
  u16* vtg   = (u16*)(ws + OFF_VTG);
  u16* attnw = (u16*)(ws + OFF_ATTNW);
  float* tO4 = (float*)(ws + OFF_TO4);
  u16* qb    = (u16*)d_out;
  u16* kb    = (u16*)((char*)d_out + 25165824);
  u16* cvp1  = (u16*)((char*)d_out + 33554432);

  // 1) all casts in one launch
  k_cast_all<<<2048, 256, 0, stream>>>(x, Wqkv, Bqkv, Aqkv, Wo, Bo, Ao,
                                       xw, wwq, aqkvb, wwo, aob);

  // 2) LoRA-A: tA = x @ Aqkv^T (split-K x4) -> xw tail (scaled by 2)
  k_gemm_bt_sk<<<dim3(4, 64, 4), 256, 0, stream>>>(xw, aqkvb, tA4, 4096, 256, 3328, 3072, 768);
  k_red4_cast<<<dim3(1, 4096), 64, 0, stream>>>(tA4, xw, 32, 3328, 3072, 2.f, (size_t)4096 * 256);

  // 3) rope table + ctr reset (true-tail region, never aliases live data)
  k_rope_tab<<<dim3(1024), 192, 0, stream>>>(pos, rtab, ctr);

  // 4) qkv GEMM, fully balanced: every block = 52 Kt (q|k) + 13 Kt (V quarter-K chunk)
  k_gemm256_qkv<<<dim3(256), 512, 0, stream>>>(xw, wwq, qk, cvp0, cvp1);

  // 5) rope-qk + V-transpose (sums 4 slabs)
  k_rope_v<<<dim3(4096, 33), 128, 0, stream>>>(qk, cvp0, cvp1, rtab, qb, kb, vtg);

  // 6) MFMA flash attention (persistent, work-queue) -> attnw (stride 3328)
  k_attn_mfma<<<dim3(512), 256, 0, stream>>>(qb, kb, vtg, attnw, ctr);

  // 7) LoRA-A out: tO = attn @ Ao^T (split-K x4) -> attnw tail (scaled by 2)
  k_gemm_bt_sk<<<dim3(4, 64, 4), 256, 0, stream>>>(attnw, aob, tO4, 4096, 256, 3328, 3072, 768);
  k_red4_cast<<<dim3(1, 4096), 64, 0, stream>>>(tO4, attnw, 32, 3328, 3072, 2.f, (size_t)4096 * 256);

  // 8) out = [attn | 2 tO] @ [Wo | Bo]^T  (K=3328)
  k_gemm256<<<dim3((3072 / 256) * (4096 / 256)), 512, 0, stream>>>(attnw, wwo, out, 4096, 3072, 3328);
}